// Round 9
// baseline (2085.513 us; speedup 1.0000x reference)
//
#include <hip/hip_runtime.h>
#include <math.h>

// ---------------- problem constants ----------------
#define NN    50000
#define EE    800000
#define CIN   64
#define HH    192
#define EDIM  16
#define GG    2048
#define H3    576   // 3*H
#define EA_BLOCKS 256
#define FRAG_ELEMS (36 * 6 * 64)   // col-blocks * chunks * lanes, per 576x192 matrix
#define G4_WLAYER 221184           // halves per combined gru4 weight layer (2*576*192)

typedef _Float16 f16;
typedef _Float16 half8 __attribute__((ext_vector_type(8)));
typedef float f32x4 __attribute__((ext_vector_type(4)));

// ---------------- helpers ----------------
__device__ __forceinline__ unsigned fmap(float f) {
    unsigned u = __float_as_uint(f);
    return (u & 0x80000000u) ? ~u : (u | 0x80000000u);
}
__device__ __forceinline__ float funmap(unsigned u) {
    if (u == 0u) return 0.0f;
    return (u & 0x80000000u) ? __uint_as_float(u ^ 0x80000000u)
                             : __uint_as_float(~u);
}

// fast transcendentals via v_exp_f32 / v_rcp_f32 (~1 ulp; fp16 storage dominates error)
__device__ __forceinline__ float fast_exp(float x) {
    return __builtin_amdgcn_exp2f(1.442695041f * x);
}
__device__ __forceinline__ float fast_sig(float x) {
    return __builtin_amdgcn_rcpf(1.f + __builtin_amdgcn_exp2f(-1.442695041f * x));
}
__device__ __forceinline__ float fast_tanh(float x) {
    return 1.f - 2.f * __builtin_amdgcn_rcpf(1.f + __builtin_amdgcn_exp2f(2.885390082f * x));
}
__device__ __forceinline__ float fast_expm1(float x) {
    return __builtin_amdgcn_exp2f(1.442695041f * x) - 1.f;
}

// async global->LDS, 16 B per lane; LDS dest = wave-uniform base + lane*16
__device__ __forceinline__ void gload_lds16(const f16* g, f16* l) {
    __builtin_amdgcn_global_load_lds(
        (const __attribute__((address_space(1))) unsigned int*)g,
        (__attribute__((address_space(3))) unsigned int*)l,
        16, 0, 0);
}

// ---------------- fp32 -> fp16 converts ----------------
__global__ void cvt_f2h(const float* __restrict__ s, f16* __restrict__ d, int n)
{
    int i = blockIdx.x * blockDim.x + threadIdx.x;
    if (i < n) d[i] = (f16)s[i];
}

struct Cvt8 { const float* s[8]; f16* d[8]; int n[8]; };
__global__ void cvt_multi(Cvt8 c)
{
    int slot = blockIdx.y;
    int i = blockIdx.x * blockDim.x + threadIdx.x;
    if (i < c.n[slot]) c.d[slot][i] = (f16)c.s[slot][i];
}

// ---------------- GRU weight repack: fragment-major for coalesced B-loads (mol GRU) ----------
struct Pack8 { const f16* s[8]; f16* d[8]; };
__global__ __launch_bounds__(256) void pack_frag(Pack8 p)
{
    int slot = blockIdx.y;
    int idx = blockIdx.x * 256 + threadIdx.x;
    if (idx >= FRAG_ELEMS) return;
    int cb   = idx / 384;          // 6*64
    int rem  = idx % 384;
    int c    = rem / 64;
    int lane = rem % 64;
    int col = cb * 16 + (lane & 15);
    int k   = c * 32 + (lane >> 4) * 8;
    *(half8*)(p.d[slot] + (size_t)idx * 8) =
        *(const half8*)(p.s[slot] + (size_t)col * 192 + k);
}

// ---------------- gru4 weight repack: (pass,chunk)-contiguous for global_load_lds staging ----
// Combined buffer per layer: frag index = (p*6 + c)*24 + m*12 + g*4 + cb, 512 halves each.
// Within frag: lane*8 halves, col = g*192 + p*64 + cb*16 + (lane&15), k = c*32 + (lane>>4)*8.
__global__ __launch_bounds__(256) void pack4(const f16* __restrict__ Wih,
                                             const f16* __restrict__ Whh,
                                             f16* __restrict__ out)
{
    int layer = blockIdx.y;
    int idx = blockIdx.x * 256 + threadIdx.x;          // [0, 432*64)
    if (idx >= 27648) return;
    int frag = idx >> 6, lane = idx & 63;
    int pc6 = frag / 24, r24 = frag % 24;
    int p = pc6 / 6, c = pc6 % 6;
    int m = r24 / 12, g = (r24 % 12) >> 2, cb = r24 & 3;
    const f16* srcm = (m == 0 ? Wih : Whh) + (size_t)layer * (H3 * HH);
    int col = g * 192 + p * 64 + cb * 16 + (lane & 15);
    int k   = c * 32 + (lane >> 4) * 8;
    *(half8*)(out + (size_t)layer * G4_WLAYER + (size_t)idx * 8) =
        *(const half8*)(srcm + (size_t)col * 192 + k);
}

// ---------------- CSR build ----------------
__global__ void hist_kernel(const int* __restrict__ idx, int* __restrict__ deg, int n, int nbins)
{
    int i = blockIdx.x * blockDim.x + threadIdx.x;
    if (i < n) {
        unsigned b = (unsigned)idx[i];
        if (b < (unsigned)nbins) atomicAdd(&deg[b], 1);
    }
}

// single-WAVE exclusive scan (serial over 64-chunks) — small arrays only
__global__ void scan_wave(const int* __restrict__ deg, int* __restrict__ rowptr,
                          unsigned* __restrict__ cursor, int n)
{
    int lane = threadIdx.x & 63;
    int carry = 0;
    for (int base = 0; base < n; base += 64) {
        int i = base + lane;
        int v = (i < n) ? deg[i] : 0;
        int x = v;
        #pragma unroll
        for (int off = 1; off < 64; off <<= 1) {
            int t = __shfl_up(x, off);
            if (lane >= off) x += t;
        }
        int ex = carry + x - v;
        if (i < n) {
            rowptr[i] = ex;
            if (cursor) cursor[i] = (unsigned)ex;
        }
        carry += __shfl(x, 63);
    }
    if (lane == 0) rowptr[n] = carry;
}

// hierarchical scan, level 1: per-1024-chunk sums
__global__ __launch_bounds__(256) void chunk_sum(const int* __restrict__ deg,
                                                 int* __restrict__ csum, int n)
{
    int base = blockIdx.x * 1024;
    int tid = threadIdx.x;
    int i0 = base + tid * 4;
    int s = 0;
    #pragma unroll
    for (int k = 0; k < 4; k++) { int i = i0 + k; if (i < n) s += deg[i]; }
    #pragma unroll
    for (int off = 32; off > 0; off >>= 1) s += __shfl_down(s, off);
    __shared__ int ws[4];
    int lane = tid & 63, w = tid >> 6;
    if (lane == 0) ws[w] = s;
    __syncthreads();
    if (tid == 0) csum[blockIdx.x] = ws[0] + ws[1] + ws[2] + ws[3];
}

// hierarchical scan, level 3: local exclusive scan + chunk offset
__global__ __launch_bounds__(256) void local_scan(const int* __restrict__ deg,
                                                  const int* __restrict__ choff,
                                                  int* __restrict__ rowptr,
                                                  unsigned* __restrict__ cursor,
                                                  int n, int nchunks)
{
    int base = blockIdx.x * 1024;
    int tid = threadIdx.x;
    int lane = tid & 63, w = tid >> 6;
    int i0 = base + tid * 4;
    int v[4];
    #pragma unroll
    for (int k = 0; k < 4; k++) { int i = i0 + k; v[k] = (i < n) ? deg[i] : 0; }
    int tsum = v[0] + v[1] + v[2] + v[3];
    int x = tsum;
    #pragma unroll
    for (int off = 1; off < 64; off <<= 1) {
        int t = __shfl_up(x, off);
        if (lane >= off) x += t;
    }
    __shared__ int wtot[4];
    if (lane == 63) wtot[w] = x;
    __syncthreads();
    int woff = 0;
    #pragma unroll
    for (int j = 0; j < 4; j++) if (j < w) woff += wtot[j];
    int ex = choff[blockIdx.x] + woff + x - tsum;
    #pragma unroll
    for (int k = 0; k < 4; k++) {
        int i = i0 + k;
        if (i < n) {
            rowptr[i] = ex;
            if (cursor) cursor[i] = (unsigned)ex;
        }
        ex += v[k];
    }
    if (blockIdx.x == 0 && tid == 0) rowptr[n] = choff[nchunks];
}

__global__ void scatter_kernel(const int* __restrict__ src, const int* __restrict__ dst,
                               unsigned* __restrict__ cursor,
                               int* __restrict__ csr_src, int* __restrict__ csr_eid, int E)
{
    int e = blockIdx.x * blockDim.x + threadIdx.x;
    if (e >= E) return;
    unsigned d = (unsigned)dst[e];
    if (d >= (unsigned)NN) return;
    unsigned p = atomicAdd(&cursor[d], 1u);
    if (p < (unsigned)E) {
        csr_src[p] = src[e];
        csr_eid[p] = e;
    }
}

// ---------------- MFMA GEMM: C[M,N] = act(A16[M,K] @ W16[N,K]^T + bias) ----------------
__global__ __launch_bounds__(256) void gemm_mfma(const f16* __restrict__ A,
                                                 const f16* __restrict__ W,
                                                 const float* __restrict__ bias,
                                                 float* __restrict__ Cf,
                                                 f16* __restrict__ Ch,
                                                 int M, int N, int K, int act)
{
    __shared__ __align__(16) f16 sA[64 * 40];
    const int tid  = threadIdx.x;
    const int lane = tid & 63;
    const int wid  = tid >> 6;
    const int wy = wid >> 1, wx = wid & 1;
    const int m0 = blockIdx.x << 6, n0 = blockIdx.y << 6;
    const int n_ = lane & 15, quad = lane >> 4;

    f32x4 acc[2][2] = {};
    int boff0 = (n0 + wx * 32 + n_) * K + quad * 8;
    int boff1 = boff0 + 16 * K;

    const int srow = tid >> 2;
    const int skc  = (tid & 3) << 3;

    for (int k0 = 0; k0 < K; k0 += 32) {
        half8 av = {};
        int gm = m0 + srow;
        if (gm < M) av = *(const half8*)(A + (size_t)gm * K + k0 + skc);
        *(half8*)(sA + srow * 40 + skc) = av;
        __syncthreads();
        half8 a0 = *(const half8*)(sA + (wy * 32 + n_) * 40 + quad * 8);
        half8 a1 = *(const half8*)(sA + (wy * 32 + 16 + n_) * 40 + quad * 8);
        half8 b0 = *(const half8*)(W + boff0 + k0);
        half8 b1 = *(const half8*)(W + boff1 + k0);
        acc[0][0] = __builtin_amdgcn_mfma_f32_16x16x32_f16(a0, b0, acc[0][0], 0, 0, 0);
        acc[0][1] = __builtin_amdgcn_mfma_f32_16x16x32_f16(a0, b1, acc[0][1], 0, 0, 0);
        acc[1][0] = __builtin_amdgcn_mfma_f32_16x16x32_f16(a1, b0, acc[1][0], 0, 0, 0);
        acc[1][1] = __builtin_amdgcn_mfma_f32_16x16x32_f16(a1, b1, acc[1][1], 0, 0, 0);
        __syncthreads();
    }
    #pragma unroll
    for (int i = 0; i < 2; i++)
        #pragma unroll
        for (int j = 0; j < 2; j++) {
            int col = n0 + wx * 32 + j * 16 + n_;
            float bv = bias ? bias[col] : 0.f;
            #pragma unroll
            for (int reg = 0; reg < 4; reg++) {
                int row = m0 + wy * 32 + i * 16 + quad * 4 + reg;
                if (row >= M) continue;
                float v = acc[i][j][reg] + bv;
                if (act == 1) v = v >= 0.f ? v : 0.01f * v;
                if (Cf) Cf[(size_t)row * N + col] = v;
                if (Ch) Ch[(size_t)row * N + col] = (f16)v;
            }
        }
}

// ---------------- legacy fused GRU (kept for small M = molecule level) ----------------
#define GRU_LDP 208
__global__ __launch_bounds__(256, 2) void gru_mfma(const f16* __restrict__ H16,
                                                   f16* __restrict__ X16,
                                                   const f16* __restrict__ Pih,
                                                   const f16* __restrict__ Phh,
                                                   const float* __restrict__ bih,
                                                   const float* __restrict__ bhh,
                                                   int M)
{
    __shared__ __align__(16) f16 sH[32 * GRU_LDP];
    __shared__ __align__(16) f16 sX[32 * GRU_LDP];
    const int tid  = threadIdx.x;
    const int lane = tid & 63;
    const int w    = tid >> 6;
    const int n_ = lane & 15, quad = lane >> 4;
    const int node0 = blockIdx.x << 5;

    {
        const int r  = tid >> 3;
        const int cb = (tid & 7) * 24;
        const int gm = node0 + r;
        if (gm < M) {
            const f16* hp = H16 + (size_t)gm * 192 + cb;
            const f16* xp = X16 + (size_t)gm * 192 + cb;
            #pragma unroll
            for (int q = 0; q < 3; q++) {
                *(half8*)(sH + r * GRU_LDP + cb + q * 8) = *(const half8*)(hp + q * 8);
                *(half8*)(sX + r * GRU_LDP + cb + q * 8) = *(const half8*)(xp + q * 8);
            }
        } else {
            half8 z = {};
            #pragma unroll
            for (int q = 0; q < 3; q++) {
                *(half8*)(sH + r * GRU_LDP + cb + q * 8) = z;
                *(half8*)(sX + r * GRU_LDP + cb + q * 8) = z;
            }
        }
    }
    __syncthreads();

    f32x4 aRZ[2][2][3] = {};
    f32x4 aIN[2][3] = {};
    f32x4 aHN[2][3] = {};
    int fb[3][3];
    #pragma unroll
    for (int g = 0; g < 3; g++)
        #pragma unroll
        for (int t = 0; t < 3; t++)
            fb[g][t] = (g * 12 + w * 3 + t) * 3072 + lane * 8;

    #pragma unroll 1
    for (int c = 0; c < 6; c++) {
        int k0 = c * 32;
        int po = c * 512;
        half8 ah0 = *(const half8*)(sH + n_ * GRU_LDP + k0 + quad * 8);
        half8 ah1 = *(const half8*)(sH + (16 + n_) * GRU_LDP + k0 + quad * 8);
        half8 ax0 = *(const half8*)(sX + n_ * GRU_LDP + k0 + quad * 8);
        half8 ax1 = *(const half8*)(sX + (16 + n_) * GRU_LDP + k0 + quad * 8);
        #pragma unroll
        for (int g = 0; g < 2; g++)
            #pragma unroll
            for (int t = 0; t < 3; t++) {
                half8 bI = *(const half8*)(Pih + fb[g][t] + po);
                half8 bH = *(const half8*)(Phh + fb[g][t] + po);
                aRZ[0][g][t] = __builtin_amdgcn_mfma_f32_16x16x32_f16(ah0, bI, aRZ[0][g][t], 0, 0, 0);
                aRZ[1][g][t] = __builtin_amdgcn_mfma_f32_16x16x32_f16(ah1, bI, aRZ[1][g][t], 0, 0, 0);
                aRZ[0][g][t] = __builtin_amdgcn_mfma_f32_16x16x32_f16(ax0, bH, aRZ[0][g][t], 0, 0, 0);
                aRZ[1][g][t] = __builtin_amdgcn_mfma_f32_16x16x32_f16(ax1, bH, aRZ[1][g][t], 0, 0, 0);
            }
        #pragma unroll
        for (int t = 0; t < 3; t++) {
            half8 bI = *(const half8*)(Pih + fb[2][t] + po);
            half8 bH = *(const half8*)(Phh + fb[2][t] + po);
            aIN[0][t] = __builtin_amdgcn_mfma_f32_16x16x32_f16(ah0, bI, aIN[0][t], 0, 0, 0);
            aIN[1][t] = __builtin_amdgcn_mfma_f32_16x16x32_f16(ah1, bI, aIN[1][t], 0, 0, 0);
            aHN[0][t] = __builtin_amdgcn_mfma_f32_16x16x32_f16(ax0, bH, aHN[0][t], 0, 0, 0);
            aHN[1][t] = __builtin_amdgcn_mfma_f32_16x16x32_f16(ax1, bH, aHN[1][t], 0, 0, 0);
        }
    }

    #pragma unroll
    for (int t = 0; t < 3; t++) {
        const int c0 = w * 48 + t * 16 + n_;
        float brz = bih[c0] + bhh[c0];
        float bzz = bih[c0 + 192] + bhh[c0 + 192];
        float bin = bih[c0 + 384], bhn = bhh[c0 + 384];
        #pragma unroll
        for (int half = 0; half < 2; half++) {
            #pragma unroll
            for (int reg = 0; reg < 4; reg++) {
                int rl = half * 16 + quad * 4 + reg;
                int node = node0 + rl;
                if (node >= M) continue;
                float hx = (float)sX[rl * GRU_LDP + c0];
                float r  = fast_sig(aRZ[half][0][t][reg] + brz);
                float z  = fast_sig(aRZ[half][1][t][reg] + bzz);
                float nn = fast_tanh(aIN[half][t][reg] + bin + r * (aHN[half][t][reg] + bhn));
                float o  = (1.f - z) * nn + z * hx;
                X16[(size_t)node * 192 + c0] = (f16)(o > 0.f ? o : 0.f);
            }
        }
    }
}

// ---------------- gru4: 128 rows/block, 3 sequential 64-col passes, LDS weight pipeline ----
// R9 = R8 pipeline + FIX: A-operand chunk index must cycle (k+1)%6 (column chunk within
// the 192-wide row), not k+1 (R8 read past the row end for chunks >= 6 -> absmax 0.036).
// Counted-vmcnt 2-deep prefetch: step k issues aload((k+1)%6)+stage(k+2), computes k,
// then s_waitcnt vmcnt(6) (stage(k+2) stays in flight across the raw s_barrier).
// Epilogue steps (uncountable loads/stores) keep a full __syncthreads().
#define G4_ROWS 128
__global__ __launch_bounds__(256, 2) void gru4_mfma(const f16* __restrict__ H16,
                                                    const f16* __restrict__ Xold,
                                                    f16* __restrict__ Xnew,
                                                    const f16* __restrict__ W4,
                                                    const float* __restrict__ bih,
                                                    const float* __restrict__ bhh,
                                                    int M)
{
    __shared__ __align__(16) f16 sB[3][12288];   // 3 x 24576 B weight chunk buffers
    const int tid  = threadIdx.x;
    const int lane = tid & 63;
    const int w    = tid >> 6;
    const int n_ = lane & 15, quad = lane >> 4;
    const int rb = blockIdx.x * G4_ROWS + w * 32;   // wave's 32 rows
    const int r0 = min(rb + n_,      M - 1);
    const int r1 = min(rb + 16 + n_, M - 1);

    half8 aA[4], aB[4];
    f32x4 acc[2][4][4] = {};   // [row-half][col-block][gate: r,z,in,hn]

#define G4_STAGE(B, PC) do {                                                   \
        const f16* gs_ = W4 + (size_t)(PC) * 12288 + (w * 6) * 512 + lane * 8; \
        f16* ls_ = &sB[B][(w * 6) * 512];                                      \
        _Pragma("unroll")                                                      \
        for (int i_ = 0; i_ < 6; i_++)                                         \
            gload_lds16(gs_ + i_ * 512, ls_ + i_ * 512);                       \
    } while (0)

#define G4_ALOAD(AB, C) do {                                                   \
        const f16* h0_ = H16  + (size_t)r0 * 192 + (C) * 32 + quad * 8;        \
        const f16* h1_ = H16  + (size_t)r1 * 192 + (C) * 32 + quad * 8;        \
        const f16* x0_ = Xold + (size_t)r0 * 192 + (C) * 32 + quad * 8;        \
        const f16* x1_ = Xold + (size_t)r1 * 192 + (C) * 32 + quad * 8;        \
        AB[0] = *(const half8*)h0_;                                            \
        AB[1] = *(const half8*)h1_;                                            \
        AB[2] = *(const half8*)x0_;                                            \
        AB[3] = *(const half8*)x1_;                                            \
    } while (0)

#define G4_COMP(AB, CUR) do {                                                  \
        _Pragma("unroll")                                                      \
        for (int cb_ = 0; cb_ < 4; cb_++) {                                    \
            const f16* bp_ = &sB[CUR][cb_ * 512 + lane * 8];                   \
            half8 rI_ = *(const half8*)(bp_);                                  \
            half8 zI_ = *(const half8*)(bp_ + 2048);                           \
            half8 nI_ = *(const half8*)(bp_ + 4096);                           \
            half8 rH_ = *(const half8*)(bp_ + 6144);                           \
            half8 zH_ = *(const half8*)(bp_ + 8192);                           \
            half8 nH_ = *(const half8*)(bp_ + 10240);                          \
            acc[0][cb_][0] = __builtin_amdgcn_mfma_f32_16x16x32_f16(AB[0], rI_, acc[0][cb_][0], 0, 0, 0); \
            acc[0][cb_][0] = __builtin_amdgcn_mfma_f32_16x16x32_f16(AB[2], rH_, acc[0][cb_][0], 0, 0, 0); \
            acc[1][cb_][0] = __builtin_amdgcn_mfma_f32_16x16x32_f16(AB[1], rI_, acc[1][cb_][0], 0, 0, 0); \
            acc[1][cb_][0] = __builtin_amdgcn_mfma_f32_16x16x32_f16(AB[3], rH_, acc[1][cb_][0], 0, 0, 0); \
            acc[0][cb_][1] = __builtin_amdgcn_mfma_f32_16x16x32_f16(AB[0], zI_, acc[0][cb_][1], 0, 0, 0); \
            acc[0][cb_][1] = __builtin_amdgcn_mfma_f32_16x16x32_f16(AB[2], zH_, acc[0][cb_][1], 0, 0, 0); \
            acc[1][cb_][1] = __builtin_amdgcn_mfma_f32_16x16x32_f16(AB[1], zI_, acc[1][cb_][1], 0, 0, 0); \
            acc[1][cb_][1] = __builtin_amdgcn_mfma_f32_16x16x32_f16(AB[3], zH_, acc[1][cb_][1], 0, 0, 0); \
            acc[0][cb_][2] = __builtin_amdgcn_mfma_f32_16x16x32_f16(AB[0], nI_, acc[0][cb_][2], 0, 0, 0); \
            acc[1][cb_][2] = __builtin_amdgcn_mfma_f32_16x16x32_f16(AB[1], nI_, acc[1][cb_][2], 0, 0, 0); \
            acc[0][cb_][3] = __builtin_amdgcn_mfma_f32_16x16x32_f16(AB[2], nH_, acc[0][cb_][3], 0, 0, 0); \
            acc[1][cb_][3] = __builtin_amdgcn_mfma_f32_16x16x32_f16(AB[3], nH_, acc[1][cb_][3], 0, 0, 0); \
        }                                                                      \
    } while (0)

#define G4_EPI(P) do {                                                         \
        _Pragma("unroll")                                                      \
        for (int cb_ = 0; cb_ < 4; cb_++) {                                    \
            int c0_ = (P) * 64 + cb_ * 16 + n_;                                \
            float brz_ = bih[c0_] + bhh[c0_];                                  \
            float bzz_ = bih[c0_ + 192] + bhh[c0_ + 192];                      \
            float bin_ = bih[c0_ + 384], bhn_ = bhh[c0_ + 384];                \
            _Pragma("unroll")                                                  \
            for (int rh_ = 0; rh_ < 2; rh_++) {                                \
                _Pragma("unroll")                                              \
                for (int rg_ = 0; rg_ < 4; rg_++) {                            \
                    int node_ = rb + rh_ * 16 + quad * 4 + rg_;                \
                    if (node_ < M) {                                           \
                        float hx_ = (float)Xold[(size_t)node_ * 192 + c0_];    \
                        float r_  = fast_sig(acc[rh_][cb_][0][rg_] + brz_);    \
                        float z_  = fast_sig(acc[rh_][cb_][1][rg_] + bzz_);    \
                        float nn_ = fast_tanh(acc[rh_][cb_][2][rg_] + bin_ + r_ * (acc[rh_][cb_][3][rg_] + bhn_)); \
                        float o_  = (1.f - z_) * nn_ + z_ * hx_;               \
                        Xnew[(size_t)node_ * 192 + c0_] = (f16)(o_ > 0.f ? o_ : 0.f); \
                    }                                                          \
                    acc[rh_][cb_][0][rg_] = 0.f;                               \
                    acc[rh_][cb_][1][rg_] = 0.f;                               \
                    acc[rh_][cb_][2][rg_] = 0.f;                               \
                    acc[rh_][cb_][3][rg_] = 0.f;                               \
                }                                                              \
            }                                                                  \
        }                                                                      \
    } while (0)

    // prologue: aload(0) first (oldest), then stage chunks 0,1
    G4_ALOAD(aA, 0);
    G4_STAGE(0, 0);
    G4_STAGE(1, 1);
    // wait: aload(0)+stage(0) complete; stage(1) stays in flight across the barrier
    asm volatile("s_waitcnt vmcnt(6)" ::: "memory");
    __builtin_amdgcn_s_barrier();
    asm volatile("" ::: "memory");

    #pragma unroll
    for (int k = 0; k < 18; k++) {
        if (k + 1 < 18) {
            if (k & 1) G4_ALOAD(aA, (k + 1) % 6); else G4_ALOAD(aB, (k + 1) % 6);
        }
        if (k + 2 < 18) G4_STAGE((k + 2) % 3, k + 2);
        if (k & 1) G4_COMP(aB, k % 3); else G4_COMP(aA, k % 3);
        if (k % 6 == 5) {
            G4_EPI(k / 6);
            if (k < 17) __syncthreads();         // full drain on epilogue steps
        } else {
            // counted wait: retire stage(k+1)+aload(k+1); keep stage(k+2) in flight
            if (k + 2 < 18) {
                asm volatile("s_waitcnt vmcnt(6)" ::: "memory");
            } else {
                asm volatile("s_waitcnt vmcnt(0)" ::: "memory");
            }
            __builtin_amdgcn_s_barrier();
            asm volatile("" ::: "memory");
        }
    }

#undef G4_STAGE
#undef G4_ALOAD
#undef G4_COMP
#undef G4_EPI
}

// ---------------- vector compose: one WAVE per output column (latency-parallel) ----------
// out[j] = sum_i v[i] * W[i*cols + j]; grid = (cols+3)/4 blocks x 4 waves.
__global__ void compose_vec2(const float* __restrict__ W, const float* __restrict__ v,
                             float* __restrict__ out, int rows, int cols)
{
    int j = blockIdx.x * 4 + (threadIdx.x >> 6);
    if (j >= cols) return;
    int lane = threadIdx.x & 63;
    float acc = 0.f;
    for (int i = lane; i < rows; i += 64) acc += v[i] * W[(size_t)i * cols + j];
    #pragma unroll
    for (int off = 32; off > 0; off >>= 1) acc += __shfl_down(acc, off);
    if (lane == 0) out[j] = acc;
}

// ---------------- edge_attr column sums -> per-block partials (no atomics) ----------------
__global__ __launch_bounds__(256) void ea_sum_kernel(const float* __restrict__ ea,
                                                     float* __restrict__ partials, int E)
{
    __shared__ float ws[4][16];
    int tid = threadIdx.x;
    int lane = tid & 63, w = tid >> 6;
    float acc[16];
    #pragma unroll
    for (int f = 0; f < 16; f++) acc[f] = 0.f;
    for (int e = blockIdx.x * blockDim.x + tid; e < E; e += gridDim.x * blockDim.x) {
        const float4* p = (const float4*)(ea + (size_t)e * 16);
        float4 v0 = p[0], v1 = p[1], v2 = p[2], v3 = p[3];
        acc[0] += v0.x; acc[1] += v0.y; acc[2] += v0.z; acc[3] += v0.w;
        acc[4] += v1.x; acc[5] += v1.y; acc[6] += v1.z; acc[7] += v1.w;
        acc[8] += v2.x; acc[9] += v2.y; acc[10] += v2.z; acc[11] += v2.w;
        acc[12] += v3.x; acc[13] += v3.y; acc[14] += v3.z; acc[15] += v3.w;
    }
    #pragma unroll
    for (int off = 32; off > 0; off >>= 1)
        #pragma unroll
        for (int f = 0; f < 16; f++) acc[f] += __shfl_down(acc[f], off);
    if (lane == 0)
        #pragma unroll
        for (int f = 0; f < 16; f++) ws[w][f] = acc[f];
    __syncthreads();
    if (tid < 16)
        partials[blockIdx.x * 16 + tid] = ws[0][tid] + ws[1][tid] + ws[2][tid] + ws[3][tid];
}

// aloop = invE * sum_{b,f} partials[b*16+f] * ve[f] — 256-thread parallel reduce
__global__ void finalize_aloop(const float* __restrict__ partials, const float* __restrict__ ve,
                               float* __restrict__ aloop, float invE, int nblk)
{
    int tid = threadIdx.x;
    int total = nblk * 16;
    float vf = ve[tid & 15];          // stride 256 preserves (i & 15)
    float s = 0.f;
    for (int i = tid; i < total; i += 256) s += partials[i] * vf;
    #pragma unroll
    for (int off = 32; off > 0; off >>= 1) s += __shfl_down(s, off);
    __shared__ float ws[4];
    if ((tid & 63) == 0) ws[tid >> 6] = s;
    __syncthreads();
    if (tid == 0) *aloop = (ws[0] + ws[1] + ws[2] + ws[3]) * invE;
}

// ---------------- per-row dots on fp16 matrix (1-2 vectors) ----------------
__global__ void row_dots_h(const f16* __restrict__ Mat, int M,
                           const float* __restrict__ v1, float* __restrict__ o1,
                           const float* __restrict__ v2, float* __restrict__ o2,
                           const float* __restrict__ bias)
{
    int row = blockIdx.x * 4 + (threadIdx.x >> 6);
    if (row >= M) return;
    int lane = threadIdx.x & 63;
    const f16* rp = Mat + (size_t)row * 192;
    float a1 = 0.f, a2 = 0.f;
    #pragma unroll
    for (int k = 0; k < 3; k++) {
        int f = lane + 64 * k;
        float x = (float)rp[f];
        a1 += x * v1[f];
        if (o2) a2 += x * v2[f];
    }
    #pragma unroll
    for (int off = 32; off > 0; off >>= 1) {
        a1 += __shfl_down(a1, off);
        a2 += __shfl_down(a2, off);
    }
    if (lane == 0) {
        o1[row] = a1 + (bias ? bias[0] : 0.f);
        if (o2) o2[row] = a2;
    }
}

// ---------------- alpha + segment max ----------------
__global__ void edge_alpha_max(const int* __restrict__ srcp, const int* __restrict__ dstp,
                               int E_real, int Etot,
                               const float* __restrict__ as_, const float* __restrict__ ad_,
                               const float* __restrict__ ea, const float* __restrict__ ve,
                               const float* __restrict__ aloop, float slope,
                               float* __restrict__ ab, unsigned* __restrict__ mb)
{
    int i = blockIdx.x * blockDim.x + threadIdx.x;
    if (i >= Etot) return;
    int s_, d_;
    float aext = 0.f;
    if (i < E_real) {
        s_ = srcp ? srcp[i] : i;
        d_ = dstp[i];
        if (ea) {
            const float4* p = (const float4*)(ea + (size_t)i * 16);
            const float4* q = (const float4*)ve;
            float4 e0 = p[0], e1 = p[1], e2 = p[2], e3 = p[3];
            float4 w0 = q[0], w1 = q[1], w2 = q[2], w3 = q[3];
            aext = e0.x * w0.x + e0.y * w0.y + e0.z * w0.z + e0.w * w0.w
                 + e1.x * w1.x + e1.y * w1.y + e1.z * w1.z + e1.w * w1.w
                 + e2.x * w2.x + e2.y * w2.y + e2.z * w2.z + e2.w * w2.w
                 + e3.x * w3.x + e3.y * w3.y + e3.z * w3.z + e3.w * w3.w;
        }
    } else {
        s_ = d_ = i - E_real;
        aext = *aloop;
    }
    float a = as_[s_] + ad_[d_] + aext;
    a = a >= 0.f ? a : slope * a;
    ab[i] = a;
    atomicMax(&mb[d_], fmap(a));
}

// ---------------- exp(alpha - max) + segment sum ----------------
__global__ void edge_exp_sum(const int* __restrict__ dstp, int E_real, int Etot,
                             float* __restrict__ ab, const unsigned* __restrict__ mb,
                             float* __restrict__ sb)
{
    int i = blockIdx.x * blockDim.x + threadIdx.x;
    if (i >= Etot) return;
    int d_ = (i < E_real) ? dstp[i] : i - E_real;
    float m = funmap(mb[d_]);
    float e = fast_exp(ab[i] - m);
    ab[i] = e;
    atomicAdd(&sb[d_], e);
}

// ---------------- CSR aggregate: Hout16[dst] = elu(sum_e w_e*F[src_e]/sum + bias), fp16 out ----
// 8-wide unrolled edge gather — 24 independent 128 B loads in flight per wave.
__global__ __launch_bounds__(256) void csr_aggregate(const int* __restrict__ rowptr,
                                                     const int* __restrict__ csr_src,
                                                     const int* __restrict__ csr_eid,
                                                     int Ndst, int nF, int nAb,
                                                     int selfloop, int selfAb,
                                                     const float* __restrict__ ab,
                                                     const float* __restrict__ sb,
                                                     const f16* __restrict__ F,
                                                     const float* __restrict__ bias,
                                                     f16* __restrict__ Hout16)
{
    int node = blockIdx.x * 4 + (threadIdx.x >> 6);
    if (node >= Ndst) return;
    int lane = threadIdx.x & 63;
    int start = rowptr[node];
    int deg = rowptr[node + 1] - start;
    deg = min(max(deg, 0), 1 << 20);
    float inv = 1.f / (sb[node] + 1e-16f);

    float acc0 = 0.f, acc1 = 0.f, acc2 = 0.f;
    for (int base = 0; base < deg; base += 64) {
        int i = base + lane;
        float wv = 0.f;
        int s = 0;
        if (i < deg) {
            int pos = start + i;
            s = csr_src ? csr_src[pos] : pos;
            if ((unsigned)s >= (unsigned)nF) s = 0;
            unsigned eid = csr_eid ? (unsigned)csr_eid[pos] : (unsigned)pos;
            if (eid >= (unsigned)nAb) eid = 0;
            wv = ab[eid];
        }
        int cnt = min(64, deg - base);
        int j = 0;
        for (; j + 8 <= cnt; j += 8) {
            float wj[8];
            const f16* fp[8];
            #pragma unroll
            for (int q = 0; q < 8; q++) {
                wj[q] = __shfl(wv, j + q);
                fp[q] = F + (size_t)__shfl(s, j + q) * 192;
            }
            float a0[8], a1[8], a2[8];
            #pragma unroll
            for (int q = 0; q < 8; q++) {
                a0[q] = (float)fp[q][lane];
                a1[q] = (float)fp[q][lane + 64];
                a2[q] = (float)fp[q][lane + 128];
            }
            #pragma unroll
            for (int q = 0; q < 8; q++) {
                acc0 += wj[q] * a0[q];
                acc1 += wj[q] * a1[q];
                acc2 += wj[q] * a2[q];
            }
        }
        for (; j < cnt; j++) {
            float wj = __shfl(wv, j);
            int   sj = __shfl(s, j);
            const f16* fr = F + (size_t)sj * 192;
            acc0 += wj * (float)fr[lane];
            acc1 += wj * (float)fr[lane + 64];
            acc2 += wj * (float)fr[lane + 128];
        }
    }
    if (selfloop) {
        unsigned eid = (unsigned)(selfAb + node);
        float wv = (eid < (unsigned)nAb) ? ab[eid] : 0.f;
        int s = min(node, nF - 1);
        const f16* fr = F + (size_t)s * 192;
        acc0 += wv * (float)fr[lane];
        acc1 += wv * (float)fr[lane + 64];
        acc2 += wv * (float)fr[lane + 128];
    }
    float h0 = acc0 * inv + bias[lane];
    float h1 = acc1 * inv + bias[lane + 64];
    float h2 = acc2 * inv + bias[lane + 128];
    f16* orow = Hout16 + (size_t)node * 192;
    orow[lane]       = (f16)(h0 > 0.f ? h0 : fast_expm1(h0));
    orow[lane + 64]  = (f16)(h1 > 0.f ? h1 : fast_expm1(h1));
    orow[lane + 128] = (f16)(h2 > 0.f ? h2 : fast_expm1(h2));
}

// ---------------- pool: per-graph wave sum over contiguous node range, relu, fp16 ----------------
__global__ void pool_csr(const int* __restrict__ brow, const f16* __restrict__ X,
                         f16* __restrict__ outg16, int G)
{
    int g = blockIdx.x * 4 + (threadIdx.x >> 6);
    if (g >= G) return;
    int lane = threadIdx.x & 63;
    float a0 = 0.f, a1 = 0.f, a2 = 0.f;
    int s = max(brow[g], 0);
    int e = min(brow[g + 1], NN);
    for (int n = s; n < e; n++) {
        const f16* xr = X + (size_t)n * 192;
        a0 += (float)xr[lane];
        a1 += (float)xr[lane + 64];
        a2 += (float)xr[lane + 128];
    }
    f16* o = outg16 + (size_t)g * 192;
    o[lane]       = (f16)(a0 > 0.f ? a0 : 0.f);
    o[lane + 64]  = (f16)(a1 > 0.f ? a1 : 0.f);
    o[lane + 128] = (f16)(a2 > 0.f ? a2 : 0.f);
}

// ---------------- launch ----------------
extern "C" void kernel_launch(void* const* d_in, const int* in_sizes, int n_in,
                              void* d_out, int out_size, void* d_ws, size_t ws_size,
                              hipStream_t stream)
{
    const float* x_in        = (const float*)d_in[0];
    const int*   ei          = (const int*)  d_in[1];
    const float* eattr       = (const float*)d_in[2];
    const int*   batch       = (const int*)  d_in[3];
    const float* lin1_W      = (const float*)d_in[4];
    const float* lin1_b      = (const float*)d_in[5];
    const float* conv0_W     = (const float*)d_in[6];
    const float* conv0_att_s = (const float*)d_in[7];
    const float* conv0_att_d = (const float*)d_in[8];
    const float* conv0_We    = (const float*)d_in[9];
    const float* conv0_att_e = (const float*)d_in[10];
    const float* conv0_b     = (const float*)d_in[11];
    const float* convs_W     = (const float*)d_in[12];
    const float* convs_att_s = (const float*)d_in[13];
    const float* convs_att_d = (const float*)d_in[14];
    const float* convs_b     = (const float*)d_in[15];
    const float* gru_Wih     = (const float*)d_in[16];
    const float* gru_Whh     = (const float*)d_in[17];
    const float* gru_bih     = (const float*)d_in[18];
    const float* gru_bhh     = (const float*)d_in[19];
    const float* mol_Wsrc    = (const float*)d_in[20];
    const float* mol_Wdst    = (const float*)d_in[21];
    const float* mol_att_s   = (const float*)d_in[22];
    const float* mol_att_d   = (const float*)d_in[23];
    const float* mol_b       = (const float*)d_in[24];
    const float* mgru_Wih    = (const float*)d_in[25];
    const float* mgru_Whh    = (const float*)d_in[26];
    const float* mgru_bih    = (const float*)d_in[27];
    const float* mgru_bhh    = (const float*)d_in[28];
    const float* lin2_W      = (const float*)d_in[29];
    const float* lin2_b      = (const float*)d_in[30];

    const int* src = ei;
    const int* dst = ei + EE;

    // ---- workspace layout ----
    char* base = (char*)d_ws;
    size_t off = 0;
    auto alloc = [&](size_t bytes) -> void* {
        void* p = base + off;
        off = (off + bytes + 63) & ~(size_t)63;
        return p;
    };
    f16*      w16    = (f16*)alloc((size_t)NN * HH * 2);
    f16*      h16    = (f16*)alloc((size_t)NN * HH * 2);
    f16*      x16    = (f16*)alloc((size_t)NN * HH * 2);
    f16*      x16b   = (f16*)alloc((size_t)NN * HH * 2);   // gru4 ping-pong
    f16*      xin16  = (f16*)alloc((size_t)NN * CIN * 2);
    float*    abuf   = (float*)alloc((size_t)(EE + NN) * 4);
    float*    asb    = (float*)alloc((size_t)NN * 4);
    float*    adb    = (float*)alloc((size_t)NN * 4);
    // NOTE: sb and mb must stay adjacent (NN*4 is 64-aligned) — zeroed with ONE memset
    float*    sb     = (float*)alloc((size_t)NN * 4);
    unsigned* mb     = (unsigned*)alloc((size_t)NN * 4);
    f16*      hg16   = (f16*)alloc((size_t)GG * HH * 2);
    f16*      outg16 = (f16*)alloc((size_t)GG * HH * 2);
    float*    adg    = (float*)alloc((size_t)GG * 4);
    // NOTE: sg and mg must stay adjacent (GG*4 is 64-aligned) — zeroed with ONE memset
    float*    sg     = (float*)alloc((size_t)GG * 4);
    unsigned* mg     = (unsigned*)alloc((size_t)GG * 4);
    int*      degb   = (int*)alloc((size_t)NN * 4);
    int*      rowptr = (int*)alloc((size_t)(NN + 1) * 4);
    unsigned* cursor = (unsigned*)alloc((size_t)NN * 4);
    int*      csr_src = (int*)alloc((size_t)EE * 4);
    int*      csr_eid = (int*)alloc((size_t)EE * 4);
    int*      bdeg   = (int*)alloc((size_t)GG * 4);
    int*      brow   = (int*)alloc((size_t)(GG + 1) * 4);
    int*      csum   = (int*)alloc(64 * 4);
    int*      choff  = (int*)alloc(65 * 4);
    float*    ve     = (float*)alloc(64);
    float*    eapart = (float*)alloc((size_t)EA_BLOCKS * 16 * 4);
    float*    vd     = (float*)alloc(HH * 4);
    float*    aloop  = (float*)alloc(64);
    f16*      lin1W16   = (f16*)alloc((size_t)HH * CIN * 2);
    f16*      conv0W16  = (f16*)alloc((size_t)HH * HH * 2);
    f16*      convsW16  = (f16*)alloc((size_t)2 * HH * HH * 2);
    f16*      gruWih16  = (f16*)alloc((size_t)3 * H3 * HH * 2);
    f16*      gruWhh16  = (f16*)alloc((size_t)3 * H3 * HH * 2);
    f16*      molWs16   = (f16*)alloc((size_t)HH * HH * 2);
    f16*      mgruWih16 = (f16*)alloc((size_t)H3 * HH * 2);
    f16*      mgruWhh16 = (f16*)alloc((size_t)H3 * HH * 2);
    // fragment-packed GRU weights (legacy layout; mol GRU uses slots 6,7)
    f16*      gruWihP   = (f16*)alloc((size_t)3 * FRAG_ELEMS * 8 * 2);
    f16*      gruWhhP   = (f16*)alloc((size_t)3 * FRAG_ELEMS * 8 * 2);
    f16*      mgruWihP  = (f16*)alloc((size_t)FRAG_ELEMS * 8 * 2);
    f16*      mgruWhhP  = (f16*)alloc((size_t)FRAG_ELEMS * 8 * 2);
    // gru4 combined (pass,chunk)-contiguous node-GRU weights: 3 layers x 442 KB
    f16*      gru4W     = (f16*)alloc((size_t)3 * G4_WLAYER * 2);
    if (off > ws_size) return;

    // ---- weight + input converts ----
    cvt_f2h<<<(NN * CIN + 255) / 256, 256, 0, stream>>>(x_in, xin16, NN * CIN);
    Cvt8 cv;
    cv.s[0] = lin1_W;   cv.d[0] = lin1W16;   cv.n[0] = HH * CIN;
    cv.s[1] = conv0_W;  cv.d[1] = conv0W16;  cv.n[1] = HH * HH;
    cv.s[2] = convs_W;  cv.d[2] = convsW16;  cv.n[2] = 2 * HH * HH;
    cv.s[3] = gru_Wih;  cv.d[3] = gruWih16;  cv.n[3] = 3 * H3 * HH;
    cv.s[4] = gru_Whh;  cv.d[4] = gruWhh16;  cv.n[4] = 3 * H3 * HH;
    cv.s[5] = mol_Wsrc; cv.d[5] = molWs16;   cv.n[5] = HH * HH;
    cv.s[6] = mgru_Wih; cv.d[6] = mgruWih16; cv.n[6] = H3 * HH;
    cv.s[7] = mgru_Whh; cv.d[7] = mgruWhh16; cv.n[7] = H3 * HH;
    cvt_multi<<<dim3((3 * H3 * HH + 255) / 256, 8), 256, 0, stream>>>(cv);

    // ---- pack mol GRU weights into legacy fragment-major layout ----
    Pack8 pk;
    const size_t WM = (size_t)H3 * HH;             // 110592 halves per matrix
    pk.s[0] = gruWih16;            pk.d[0] = gruWihP;
    pk.s[1] = gruWih16 + WM;       pk.d[1] = gruWihP + WM;
    pk.s[2] = gruWih16 + 2 * WM;   pk.d[2] = gruWihP + 2 * WM;
    pk.s[3] = gruWhh16;            pk.d[3] = gruWhhP;
    pk.s[4] = gruWhh16 + WM;       pk.d[4] = gruWhhP + WM;
    pk.s[5] = gruWhh16 + 2 * WM;   pk.d[5] = gruWhhP + 2 * WM;
    pk.s[6] = mgruWih16;           pk.d[6] = mgruWihP;
    pk.s[7] = mgruWhh16;           pk.d[7] = mgruWhhP;
    pack_frag<<<dim3((FRAG_ELEMS + 255) / 256, 8), 256, 0, stream>>>(pk);

    // ---- pack node GRU weights into gru4 (pass,chunk)-contiguous layout ----
    pack4<<<dim3(108, 3), 256, 0, stream>>>(gruWih16, gruWhh16, gru4W);

    // ---- CSR build ----
    const int nchunks = (NN + 1023) / 1024;   // 49
    hipMemsetAsync(degb, 0, NN * sizeof(int), stream);
    hist_kernel<<<(EE + 255) / 256, 256, 0, stream>>>(dst, degb, EE, NN);
    chunk_sum<<<nchunks, 256, 0, stream>>>(degb, csum, NN);
    scan_wave<<<1, 64, 0, stream>>>(csum, choff, nullptr, nchunks);
    local_scan<<<nchunks, 256, 0, stream>>>(degb, choff, rowptr, cursor, NN, nchunks);
    scatter_kernel<<<(EE + 255) / 256, 256, 0, stream>>>(src, dst, cursor, csr_src, csr_eid, EE);
    // batch scan (GG=2048): hierarchical (csum/choff reused sequentially on-stream)
    hipMemsetAsync(bdeg, 0, GG * sizeof(int), stream);
    hist_kernel<<<(NN + 255) / 256, 256, 0, stream>>>(batch, bdeg, NN, GG);
    chunk_sum<<<2, 256, 0, stream>>>(bdeg, csum, GG);
    scan_wave<<<1, 64, 0, stream>>>(csum, choff, nullptr, 2);
    local_scan<<<2, 256, 0, stream>>>(bdeg, choff, brow, nullptr, GG, 2);

    // ---- conv0 prep ----
    compose_vec2<<<(EDIM + 3) / 4, 256, 0, stream>>>(conv0_We, conv0_att_e, ve, HH, EDIM);
    ea_sum_kernel<<<EA_BLOCKS, 256, 0, stream>>>(eattr, eapart, EE);
    finalize_aloop<<<1, 256, 0, stream>>>(eapart, ve, aloop, 1.0f / EE, EA_BLOCKS);

    const dim3 gemmGrid((NN + 63) / 64, HH / 64);
    const int g4grid = (NN + G4_ROWS - 1) / G4_ROWS;   // 391

    // ping-pong node feature buffers (gru4 cannot write in place)
    f16* xcur = x16;
    f16* xnxt = x16b;

    // ---- lin1 ----
    gemm_mfma<<<gemmGrid, 256, 0, stream>>>(xin16, lin1W16, lin1_b, nullptr, xcur, NN, HH, CIN, 1);

    // ---- conv0 (edge feats + self loops, slope 0.2) ----
    gemm_mfma<<<gemmGrid, 256, 0, stream>>>(xcur, conv0W16, nullptr, nullptr, w16, NN, HH, HH, 0);
    row_dots_h<<<(NN + 3) / 4, 256, 0, stream>>>(w16, NN, conv0_att_s, asb, conv0_att_d, adb, nullptr);
    hipMemsetAsync(sb, 0, NN * 8, stream);   // zeroes sb AND mb (adjacent)
    edge_alpha_max<<<(EE + NN + 255) / 256, 256, 0, stream>>>(src, dst, EE, EE + NN, asb, adb,
                                                              eattr, ve, aloop, 0.2f, abuf, mb);
    edge_exp_sum<<<(EE + NN + 255) / 256, 256, 0, stream>>>(dst, EE, EE + NN, abuf, mb, sb);
    csr_aggregate<<<(NN + 3) / 4, 256, 0, stream>>>(rowptr, csr_src, csr_eid, NN, NN, EE + NN,
                                                    1, EE, abuf, sb, w16, conv0_b, h16);
    gru4_mfma<<<g4grid, 256, 0, stream>>>(h16, xcur, xnxt, gru4W, gru_bih, gru_bhh, NN);
    { f16* tmp = xcur; xcur = xnxt; xnxt = tmp; }

    // ---- remaining atom convs (no self loops, slope 0.01) ----
    for (int l = 0; l < 2; l++) {
        gemm_mfma<<<gemmGrid, 256, 0, stream>>>(xcur, convsW16 + (size_t)l * HH * HH,
                                                nullptr, nullptr, w16, NN, HH, HH, 0);
        row_dots_h<<<(NN + 3) / 4, 256, 0, stream>>>(w16, NN, convs_att_s + l * HH, asb,
                                                     convs_att_d + l * HH, adb, nullptr);
        hipMemsetAsync(sb, 0, NN * 8, stream);   // sb + mb
        edge_alpha_max<<<(EE + 255) / 256, 256, 0, stream>>>(src, dst, EE, EE, asb, adb,
                                                             nullptr, nullptr, nullptr, 0.01f, abuf, mb);
        edge_exp_sum<<<(EE + 255) / 256, 256, 0, stream>>>(dst, EE, EE, abuf, mb, sb);
        csr_aggregate<<<(NN + 3) / 4, 256, 0, stream>>>(rowptr, csr_src, csr_eid, NN, NN, EE,
                                                        0, 0, abuf, sb, w16, convs_b + l * HH, h16);
        gru4_mfma<<<g4grid, 256, 0, stream>>>(h16, xcur, xnxt,
                                              gru4W + (size_t)(l + 1) * G4_WLAYER,
                                              gru_bih + (size_t)(l + 1) * H3,
                                              gru_bhh + (size_t)(l + 1) * H3, NN);
        { f16* tmp = xcur; xcur = xnxt; xnxt = tmp; }
    }

    // ---- molecule readout ----
    pool_csr<<<(GG + 3) / 4, 256, 0, stream>>>(brow, xcur, outg16, GG);
    gemm_mfma<<<gemmGrid, 256, 0, stream>>>(xcur, molWs16, nullptr, nullptr, w16, NN, HH, HH, 0);
    row_dots_h<<<(NN + 3) / 4, 256, 0, stream>>>(w16, NN, mol_att_s, asb, nullptr, nullptr, nullptr);
    compose_vec2<<<(HH + 3) / 4, 256, 0, stream>>>(mol_Wdst, mol_att_d, vd, HH, HH);

    for (int t = 0; t < 2; t++) {
        row_dots_h<<<(GG + 3) / 4, 256, 0, stream>>>(outg16, GG, vd, adg, nullptr, nullptr, nullptr);
        hipMemsetAsync(sg, 0, GG * 8, stream);   // sg + mg (adjacent)
        edge_alpha_max<<<(NN + 255) / 256, 256, 0, stream>>>(nullptr, batch, NN, NN, asb, adg,
                                                             nullptr, nullptr, nullptr, 0.01f, abuf, mg);
        edge_exp_sum<<<(NN + 255) / 256, 256, 0, stream>>>(batch, NN, NN, abuf, mg, sg);
        csr_aggregate<<<(GG + 3) / 4, 256, 0, stream>>>(brow, nullptr, nullptr, GG, NN, NN,
                                                        0, 0, abuf, sg, w16, mol_b, hg16);
        gru_mfma<<<(GG + 31) / 32, 256, 0, stream>>>(hg16, outg16, mgruWihP, mgruWhhP,
                                                     mgru_bih, mgru_bhh, GG);
    }

    // ---- final linear ----
    row_dots_h<<<(GG + 3) / 4, 256, 0, stream>>>(outg16, GG, lin2_W, (float*)d_out,
                                                 nullptr, nullptr, lin2_b);
}

// Round 10
// 1054.125 us; speedup vs baseline: 1.9784x; 1.9784x over previous
//
#include <hip/hip_runtime.h>
#include <math.h>

// ---------------- problem constants ----------------
#define NN    50000
#define EE    800000
#define CIN   64
#define HH    192
#define EDIM  16
#define GG    2048
#define H3    576   // 3*H
#define EA_BLOCKS 256
#define FRAG_ELEMS (36 * 6 * 64)   // col-blocks * chunks * lanes, per 576x192 matrix
#define G4_WLAYER 221184           // halves per combined gru4 weight layer (2*576*192)

typedef _Float16 f16;
typedef _Float16 half8 __attribute__((ext_vector_type(8)));
typedef float f32x4 __attribute__((ext_vector_type(4)));

// ---------------- helpers ----------------
__device__ __forceinline__ unsigned fmap(float f) {
    unsigned u = __float_as_uint(f);
    return (u & 0x80000000u) ? ~u : (u | 0x80000000u);
}
__device__ __forceinline__ float funmap(unsigned u) {
    if (u == 0u) return 0.0f;
    return (u & 0x80000000u) ? __uint_as_float(u ^ 0x80000000u)
                             : __uint_as_float(~u);
}

// fast transcendentals via v_exp_f32 / v_rcp_f32 (~1 ulp; fp16 storage dominates error)
__device__ __forceinline__ float fast_exp(float x) {
    return __builtin_amdgcn_exp2f(1.442695041f * x);
}
__device__ __forceinline__ float fast_sig(float x) {
    return __builtin_amdgcn_rcpf(1.f + __builtin_amdgcn_exp2f(-1.442695041f * x));
}
__device__ __forceinline__ float fast_tanh(float x) {
    return 1.f - 2.f * __builtin_amdgcn_rcpf(1.f + __builtin_amdgcn_exp2f(2.885390082f * x));
}
__device__ __forceinline__ float fast_expm1(float x) {
    return __builtin_amdgcn_exp2f(1.442695041f * x) - 1.f;
}

// async global->LDS, 16 B per lane; LDS dest = wave-uniform base + lane*16
__device__ __forceinline__ void gload_lds16(const f16* g, f16* l) {
    __builtin_amdgcn_global_load_lds(
        (const __attribute__((address_space(1))) unsigned int*)g,
        (__attribute__((address_space(3))) unsigned int*)l,
        16, 0, 0);
}

// ---------------- fp32 -> fp16 converts ----------------
__global__ void cvt_f2h(const float* __restrict__ s, f16* __restrict__ d, int n)
{
    int i = blockIdx.x * blockDim.x + threadIdx.x;
    if (i < n) d[i] = (f16)s[i];
}

struct Cvt8 { const float* s[8]; f16* d[8]; int n[8]; };
__global__ void cvt_multi(Cvt8 c)
{
    int slot = blockIdx.y;
    int i = blockIdx.x * blockDim.x + threadIdx.x;
    if (i < c.n[slot]) c.d[slot][i] = (f16)c.s[slot][i];
}

// ---------------- GRU weight repack: fragment-major for coalesced B-loads (mol GRU) ----------
struct Pack8 { const f16* s[8]; f16* d[8]; };
__global__ __launch_bounds__(256) void pack_frag(Pack8 p)
{
    int slot = blockIdx.y;
    int idx = blockIdx.x * 256 + threadIdx.x;
    if (idx >= FRAG_ELEMS) return;
    int cb   = idx / 384;          // 6*64
    int rem  = idx % 384;
    int c    = rem / 64;
    int lane = rem % 64;
    int col = cb * 16 + (lane & 15);
    int k   = c * 32 + (lane >> 4) * 8;
    *(half8*)(p.d[slot] + (size_t)idx * 8) =
        *(const half8*)(p.s[slot] + (size_t)col * 192 + k);
}

// ---------------- gru4 weight repack: (pass,chunk)-contiguous for global_load_lds staging ----
__global__ __launch_bounds__(256) void pack4(const f16* __restrict__ Wih,
                                             const f16* __restrict__ Whh,
                                             f16* __restrict__ out)
{
    int layer = blockIdx.y;
    int idx = blockIdx.x * 256 + threadIdx.x;          // [0, 432*64)
    if (idx >= 27648) return;
    int frag = idx >> 6, lane = idx & 63;
    int pc6 = frag / 24, r24 = frag % 24;
    int p = pc6 / 6, c = pc6 % 6;
    int m = r24 / 12, g = (r24 % 12) >> 2, cb = r24 & 3;
    const f16* srcm = (m == 0 ? Wih : Whh) + (size_t)layer * (H3 * HH);
    int col = g * 192 + p * 64 + cb * 16 + (lane & 15);
    int k   = c * 32 + (lane >> 4) * 8;
    *(half8*)(out + (size_t)layer * G4_WLAYER + (size_t)idx * 8) =
        *(const half8*)(srcm + (size_t)col * 192 + k);
}

// ---------------- CSR build ----------------
__global__ void hist_kernel(const int* __restrict__ idx, int* __restrict__ deg, int n, int nbins)
{
    int i = blockIdx.x * blockDim.x + threadIdx.x;
    if (i < n) {
        unsigned b = (unsigned)idx[i];
        if (b < (unsigned)nbins) atomicAdd(&deg[b], 1);
    }
}

// single-WAVE exclusive scan (serial over 64-chunks) — small arrays only
__global__ void scan_wave(const int* __restrict__ deg, int* __restrict__ rowptr,
                          unsigned* __restrict__ cursor, int n)
{
    int lane = threadIdx.x & 63;
    int carry = 0;
    for (int base = 0; base < n; base += 64) {
        int i = base + lane;
        int v = (i < n) ? deg[i] : 0;
        int x = v;
        #pragma unroll
        for (int off = 1; off < 64; off <<= 1) {
            int t = __shfl_up(x, off);
            if (lane >= off) x += t;
        }
        int ex = carry + x - v;
        if (i < n) {
            rowptr[i] = ex;
            if (cursor) cursor[i] = (unsigned)ex;
        }
        carry += __shfl(x, 63);
    }
    if (lane == 0) rowptr[n] = carry;
}

// hierarchical scan, level 1: per-1024-chunk sums
__global__ __launch_bounds__(256) void chunk_sum(const int* __restrict__ deg,
                                                 int* __restrict__ csum, int n)
{
    int base = blockIdx.x * 1024;
    int tid = threadIdx.x;
    int i0 = base + tid * 4;
    int s = 0;
    #pragma unroll
    for (int k = 0; k < 4; k++) { int i = i0 + k; if (i < n) s += deg[i]; }
    #pragma unroll
    for (int off = 32; off > 0; off >>= 1) s += __shfl_down(s, off);
    __shared__ int ws[4];
    int lane = tid & 63, w = tid >> 6;
    if (lane == 0) ws[w] = s;
    __syncthreads();
    if (tid == 0) csum[blockIdx.x] = ws[0] + ws[1] + ws[2] + ws[3];
}

// hierarchical scan, level 3: local exclusive scan + chunk offset
__global__ __launch_bounds__(256) void local_scan(const int* __restrict__ deg,
                                                  const int* __restrict__ choff,
                                                  int* __restrict__ rowptr,
                                                  unsigned* __restrict__ cursor,
                                                  int n, int nchunks)
{
    int base = blockIdx.x * 1024;
    int tid = threadIdx.x;
    int lane = tid & 63, w = tid >> 6;
    int i0 = base + tid * 4;
    int v[4];
    #pragma unroll
    for (int k = 0; k < 4; k++) { int i = i0 + k; v[k] = (i < n) ? deg[i] : 0; }
    int tsum = v[0] + v[1] + v[2] + v[3];
    int x = tsum;
    #pragma unroll
    for (int off = 1; off < 64; off <<= 1) {
        int t = __shfl_up(x, off);
        if (lane >= off) x += t;
    }
    __shared__ int wtot[4];
    if (lane == 63) wtot[w] = x;
    __syncthreads();
    int woff = 0;
    #pragma unroll
    for (int j = 0; j < 4; j++) if (j < w) woff += wtot[j];
    int ex = choff[blockIdx.x] + woff + x - tsum;
    #pragma unroll
    for (int k = 0; k < 4; k++) {
        int i = i0 + k;
        if (i < n) {
            rowptr[i] = ex;
            if (cursor) cursor[i] = (unsigned)ex;
        }
        ex += v[k];
    }
    if (blockIdx.x == 0 && tid == 0) rowptr[n] = choff[nchunks];
}

__global__ void scatter_kernel(const int* __restrict__ src, const int* __restrict__ dst,
                               unsigned* __restrict__ cursor,
                               int* __restrict__ csr_src, int* __restrict__ csr_eid, int E)
{
    int e = blockIdx.x * blockDim.x + threadIdx.x;
    if (e >= E) return;
    unsigned d = (unsigned)dst[e];
    if (d >= (unsigned)NN) return;
    unsigned p = atomicAdd(&cursor[d], 1u);
    if (p < (unsigned)E) {
        csr_src[p] = src[e];
        csr_eid[p] = e;
    }
}

// ---------------- MFMA GEMM: C[M,N] = act(A16[M,K] @ W16[N,K]^T + bias) ----------------
__global__ __launch_bounds__(256) void gemm_mfma(const f16* __restrict__ A,
                                                 const f16* __restrict__ W,
                                                 const float* __restrict__ bias,
                                                 float* __restrict__ Cf,
                                                 f16* __restrict__ Ch,
                                                 int M, int N, int K, int act)
{
    __shared__ __align__(16) f16 sA[64 * 40];
    const int tid  = threadIdx.x;
    const int lane = tid & 63;
    const int wid  = tid >> 6;
    const int wy = wid >> 1, wx = wid & 1;
    const int m0 = blockIdx.x << 6, n0 = blockIdx.y << 6;
    const int n_ = lane & 15, quad = lane >> 4;

    f32x4 acc[2][2] = {};
    int boff0 = (n0 + wx * 32 + n_) * K + quad * 8;
    int boff1 = boff0 + 16 * K;

    const int srow = tid >> 2;
    const int skc  = (tid & 3) << 3;

    for (int k0 = 0; k0 < K; k0 += 32) {
        half8 av = {};
        int gm = m0 + srow;
        if (gm < M) av = *(const half8*)(A + (size_t)gm * K + k0 + skc);
        *(half8*)(sA + srow * 40 + skc) = av;
        __syncthreads();
        half8 a0 = *(const half8*)(sA + (wy * 32 + n_) * 40 + quad * 8);
        half8 a1 = *(const half8*)(sA + (wy * 32 + 16 + n_) * 40 + quad * 8);
        half8 b0 = *(const half8*)(W + boff0 + k0);
        half8 b1 = *(const half8*)(W + boff1 + k0);
        acc[0][0] = __builtin_amdgcn_mfma_f32_16x16x32_f16(a0, b0, acc[0][0], 0, 0, 0);
        acc[0][1] = __builtin_amdgcn_mfma_f32_16x16x32_f16(a0, b1, acc[0][1], 0, 0, 0);
        acc[1][0] = __builtin_amdgcn_mfma_f32_16x16x32_f16(a1, b0, acc[1][0], 0, 0, 0);
        acc[1][1] = __builtin_amdgcn_mfma_f32_16x16x32_f16(a1, b1, acc[1][1], 0, 0, 0);
        __syncthreads();
    }
    #pragma unroll
    for (int i = 0; i < 2; i++)
        #pragma unroll
        for (int j = 0; j < 2; j++) {
            int col = n0 + wx * 32 + j * 16 + n_;
            float bv = bias ? bias[col] : 0.f;
            #pragma unroll
            for (int reg = 0; reg < 4; reg++) {
                int row = m0 + wy * 32 + i * 16 + quad * 4 + reg;
                if (row >= M) continue;
                float v = acc[i][j][reg] + bv;
                if (act == 1) v = v >= 0.f ? v : 0.01f * v;
                if (Cf) Cf[(size_t)row * N + col] = v;
                if (Ch) Ch[(size_t)row * N + col] = (f16)v;
            }
        }
}

// ---------------- legacy fused GRU (kept for small M = molecule level) ----------------
#define GRU_LDP 208
__global__ __launch_bounds__(256, 2) void gru_mfma(const f16* __restrict__ H16,
                                                   f16* __restrict__ X16,
                                                   const f16* __restrict__ Pih,
                                                   const f16* __restrict__ Phh,
                                                   const float* __restrict__ bih,
                                                   const float* __restrict__ bhh,
                                                   int M)
{
    __shared__ __align__(16) f16 sH[32 * GRU_LDP];
    __shared__ __align__(16) f16 sX[32 * GRU_LDP];
    const int tid  = threadIdx.x;
    const int lane = tid & 63;
    const int w    = tid >> 6;
    const int n_ = lane & 15, quad = lane >> 4;
    const int node0 = blockIdx.x << 5;

    {
        const int r  = tid >> 3;
        const int cb = (tid & 7) * 24;
        const int gm = node0 + r;
        if (gm < M) {
            const f16* hp = H16 + (size_t)gm * 192 + cb;
            const f16* xp = X16 + (size_t)gm * 192 + cb;
            #pragma unroll
            for (int q = 0; q < 3; q++) {
                *(half8*)(sH + r * GRU_LDP + cb + q * 8) = *(const half8*)(hp + q * 8);
                *(half8*)(sX + r * GRU_LDP + cb + q * 8) = *(const half8*)(xp + q * 8);
            }
        } else {
            half8 z = {};
            #pragma unroll
            for (int q = 0; q < 3; q++) {
                *(half8*)(sH + r * GRU_LDP + cb + q * 8) = z;
                *(half8*)(sX + r * GRU_LDP + cb + q * 8) = z;
            }
        }
    }
    __syncthreads();

    f32x4 aRZ[2][2][3] = {};
    f32x4 aIN[2][3] = {};
    f32x4 aHN[2][3] = {};
    int fb[3][3];
    #pragma unroll
    for (int g = 0; g < 3; g++)
        #pragma unroll
        for (int t = 0; t < 3; t++)
            fb[g][t] = (g * 12 + w * 3 + t) * 3072 + lane * 8;

    #pragma unroll 1
    for (int c = 0; c < 6; c++) {
        int k0 = c * 32;
        int po = c * 512;
        half8 ah0 = *(const half8*)(sH + n_ * GRU_LDP + k0 + quad * 8);
        half8 ah1 = *(const half8*)(sH + (16 + n_) * GRU_LDP + k0 + quad * 8);
        half8 ax0 = *(const half8*)(sX + n_ * GRU_LDP + k0 + quad * 8);
        half8 ax1 = *(const half8*)(sX + (16 + n_) * GRU_LDP + k0 + quad * 8);
        #pragma unroll
        for (int g = 0; g < 2; g++)
            #pragma unroll
            for (int t = 0; t < 3; t++) {
                half8 bI = *(const half8*)(Pih + fb[g][t] + po);
                half8 bH = *(const half8*)(Phh + fb[g][t] + po);
                aRZ[0][g][t] = __builtin_amdgcn_mfma_f32_16x16x32_f16(ah0, bI, aRZ[0][g][t], 0, 0, 0);
                aRZ[1][g][t] = __builtin_amdgcn_mfma_f32_16x16x32_f16(ah1, bI, aRZ[1][g][t], 0, 0, 0);
                aRZ[0][g][t] = __builtin_amdgcn_mfma_f32_16x16x32_f16(ax0, bH, aRZ[0][g][t], 0, 0, 0);
                aRZ[1][g][t] = __builtin_amdgcn_mfma_f32_16x16x32_f16(ax1, bH, aRZ[1][g][t], 0, 0, 0);
            }
        #pragma unroll
        for (int t = 0; t < 3; t++) {
            half8 bI = *(const half8*)(Pih + fb[2][t] + po);
            half8 bH = *(const half8*)(Phh + fb[2][t] + po);
            aIN[0][t] = __builtin_amdgcn_mfma_f32_16x16x32_f16(ah0, bI, aIN[0][t], 0, 0, 0);
            aIN[1][t] = __builtin_amdgcn_mfma_f32_16x16x32_f16(ah1, bI, aIN[1][t], 0, 0, 0);
            aHN[0][t] = __builtin_amdgcn_mfma_f32_16x16x32_f16(ax0, bH, aHN[0][t], 0, 0, 0);
            aHN[1][t] = __builtin_amdgcn_mfma_f32_16x16x32_f16(ax1, bH, aHN[1][t], 0, 0, 0);
        }
    }

    #pragma unroll
    for (int t = 0; t < 3; t++) {
        const int c0 = w * 48 + t * 16 + n_;
        float brz = bih[c0] + bhh[c0];
        float bzz = bih[c0 + 192] + bhh[c0 + 192];
        float bin = bih[c0 + 384], bhn = bhh[c0 + 384];
        #pragma unroll
        for (int half = 0; half < 2; half++) {
            #pragma unroll
            for (int reg = 0; reg < 4; reg++) {
                int rl = half * 16 + quad * 4 + reg;
                int node = node0 + rl;
                if (node >= M) continue;
                float hx = (float)sX[rl * GRU_LDP + c0];
                float r  = fast_sig(aRZ[half][0][t][reg] + brz);
                float z  = fast_sig(aRZ[half][1][t][reg] + bzz);
                float nn = fast_tanh(aIN[half][t][reg] + bin + r * (aHN[half][t][reg] + bhn));
                float o  = (1.f - z) * nn + z * hx;
                X16[(size_t)node * 192 + c0] = (f16)(o > 0.f ? o : 0.f);
            }
        }
    }
}

// ---------------- gru4: 128 rows/block, 3 sequential 64-col passes, LDS weight pipeline ----
// R10: REVERTED to the R7 schedule (measured 58.8us, correct). R9's counted-vmcnt +
// per-step "memory"-clobber asm forced the acc[2][4][4] accumulators out of AGPRs into
// scratch (WRITE_SIZE 947 MB = 100k threads x 512 B x 18 steps) -> 6x regression.
// Plain __syncthreads per step keeps the compiler's AGPR allocation intact.
#define G4_ROWS 128
__global__ __launch_bounds__(256, 2) void gru4_mfma(const f16* __restrict__ H16,
                                                    const f16* __restrict__ Xold,
                                                    f16* __restrict__ Xnew,
                                                    const f16* __restrict__ W4,
                                                    const float* __restrict__ bih,
                                                    const float* __restrict__ bhh,
                                                    int M)
{
    __shared__ __align__(16) f16 sB[2][12288];   // 2 x 24576 B weight chunk buffers
    const int tid  = threadIdx.x;
    const int lane = tid & 63;
    const int w    = tid >> 6;
    const int n_ = lane & 15, quad = lane >> 4;
    const int rb = blockIdx.x * G4_ROWS + w * 32;   // wave's 32 rows
    const int r0 = min(rb + n_,      M - 1);
    const int r1 = min(rb + 16 + n_, M - 1);

    half8 aA[4], aB[4];
    f32x4 acc[2][4][4] = {};   // [row-half][col-block][gate: r,z,in,hn]

#define G4_STAGE(B, PC) do {                                                   \
        const f16* gs_ = W4 + (size_t)(PC) * 12288 + (w * 6) * 512 + lane * 8; \
        f16* ls_ = &sB[B][(w * 6) * 512];                                      \
        _Pragma("unroll")                                                      \
        for (int i_ = 0; i_ < 6; i_++)                                         \
            gload_lds16(gs_ + i_ * 512, ls_ + i_ * 512);                       \
    } while (0)

#define G4_ALOAD(AB, C) do {                                                   \
        const f16* h0_ = H16  + (size_t)r0 * 192 + (C) * 32 + quad * 8;        \
        const f16* h1_ = H16  + (size_t)r1 * 192 + (C) * 32 + quad * 8;        \
        const f16* x0_ = Xold + (size_t)r0 * 192 + (C) * 32 + quad * 8;        \
        const f16* x1_ = Xold + (size_t)r1 * 192 + (C) * 32 + quad * 8;        \
        AB[0] = *(const half8*)h0_;                                            \
        AB[1] = *(const half8*)h1_;                                            \
        AB[2] = *(const half8*)x0_;                                            \
        AB[3] = *(const half8*)x1_;                                            \
    } while (0)

#define G4_COMP(AB, CUR) do {                                                  \
        _Pragma("unroll")                                                      \
        for (int cb_ = 0; cb_ < 4; cb_++) {                                    \
            const f16* bp_ = &sB[CUR][cb_ * 512 + lane * 8];                   \
            half8 rI_ = *(const half8*)(bp_);                                  \
            half8 zI_ = *(const half8*)(bp_ + 2048);                           \
            half8 nI_ = *(const half8*)(bp_ + 4096);                           \
            half8 rH_ = *(const half8*)(bp_ + 6144);                           \
            half8 zH_ = *(const half8*)(bp_ + 8192);                           \
            half8 nH_ = *(const half8*)(bp_ + 10240);                          \
            acc[0][cb_][0] = __builtin_amdgcn_mfma_f32_16x16x32_f16(AB[0], rI_, acc[0][cb_][0], 0, 0, 0); \
            acc[0][cb_][0] = __builtin_amdgcn_mfma_f32_16x16x32_f16(AB[2], rH_, acc[0][cb_][0], 0, 0, 0); \
            acc[1][cb_][0] = __builtin_amdgcn_mfma_f32_16x16x32_f16(AB[1], rI_, acc[1][cb_][0], 0, 0, 0); \
            acc[1][cb_][0] = __builtin_amdgcn_mfma_f32_16x16x32_f16(AB[3], rH_, acc[1][cb_][0], 0, 0, 0); \
            acc[0][cb_][1] = __builtin_amdgcn_mfma_f32_16x16x32_f16(AB[0], zI_, acc[0][cb_][1], 0, 0, 0); \
            acc[0][cb_][1] = __builtin_amdgcn_mfma_f32_16x16x32_f16(AB[2], zH_, acc[0][cb_][1], 0, 0, 0); \
            acc[1][cb_][1] = __builtin_amdgcn_mfma_f32_16x16x32_f16(AB[1], zI_, acc[1][cb_][1], 0, 0, 0); \
            acc[1][cb_][1] = __builtin_amdgcn_mfma_f32_16x16x32_f16(AB[3], zH_, acc[1][cb_][1], 0, 0, 0); \
            acc[0][cb_][2] = __builtin_amdgcn_mfma_f32_16x16x32_f16(AB[0], nI_, acc[0][cb_][2], 0, 0, 0); \
            acc[1][cb_][2] = __builtin_amdgcn_mfma_f32_16x16x32_f16(AB[1], nI_, acc[1][cb_][2], 0, 0, 0); \
            acc[0][cb_][3] = __builtin_amdgcn_mfma_f32_16x16x32_f16(AB[2], nH_, acc[0][cb_][3], 0, 0, 0); \
            acc[1][cb_][3] = __builtin_amdgcn_mfma_f32_16x16x32_f16(AB[3], nH_, acc[1][cb_][3], 0, 0, 0); \
        }                                                                      \
    } while (0)

#define G4_EPI(P) do {                                                         \
        _Pragma("unroll")                                                      \
        for (int cb_ = 0; cb_ < 4; cb_++) {                                    \
            int c0_ = (P) * 64 + cb_ * 16 + n_;                                \
            float brz_ = bih[c0_] + bhh[c0_];                                  \
            float bzz_ = bih[c0_ + 192] + bhh[c0_ + 192];                      \
            float bin_ = bih[c0_ + 384], bhn_ = bhh[c0_ + 384];                \
            _Pragma("unroll")                                                  \
            for (int rh_ = 0; rh_ < 2; rh_++) {                                \
                _Pragma("unroll")                                              \
                for (int rg_ = 0; rg_ < 4; rg_++) {                            \
                    int node_ = rb + rh_ * 16 + quad * 4 + rg_;                \
                    if (node_ < M) {                                           \
                        float hx_ = (float)Xold[(size_t)node_ * 192 + c0_];    \
                        float r_  = fast_sig(acc[rh_][cb_][0][rg_] + brz_);    \
                        float z_  = fast_sig(acc[rh_][cb_][1][rg_] + bzz_);    \
                        float nn_ = fast_tanh(acc[rh_][cb_][2][rg_] + bin_ + r_ * (acc[rh_][cb_][3][rg_] + bhn_)); \
                        float o_  = (1.f - z_) * nn_ + z_ * hx_;               \
                        Xnew[(size_t)node_ * 192 + c0_] = (f16)(o_ > 0.f ? o_ : 0.f); \
                    }                                                          \
                    acc[rh_][cb_][0][rg_] = 0.f;                               \
                    acc[rh_][cb_][1][rg_] = 0.f;                               \
                    acc[rh_][cb_][2][rg_] = 0.f;                               \
                    acc[rh_][cb_][3][rg_] = 0.f;                               \
                }                                                              \
            }                                                                  \
        }                                                                      \
    } while (0)

#define G4_STEP(ACUR, ANXT, PC) do {                                           \
        if ((PC) < 17) {                                                       \
            G4_STAGE(((PC) + 1) & 1, (PC) + 1);                                \
            G4_ALOAD(ANXT, ((PC) + 1) % 6);                                    \
        }                                                                      \
        G4_COMP(ACUR, (PC) & 1);                                               \
        if (((PC) % 6) == 5) G4_EPI((PC) / 6);                                 \
        __syncthreads();                                                       \
    } while (0)

    // prologue: stage chunk 0 + A chunk 0
    G4_STAGE(0, 0);
    G4_ALOAD(aA, 0);
    __syncthreads();

    for (int pc = 0; pc < 18; pc += 2) {
        G4_STEP(aA, aB, pc);
        G4_STEP(aB, aA, pc + 1);
    }

#undef G4_STAGE
#undef G4_ALOAD
#undef G4_COMP
#undef G4_EPI
#undef G4_STEP
}

// ---------------- vector compose: one WAVE per output column (latency-parallel) ----------
__global__ void compose_vec2(const float* __restrict__ W, const float* __restrict__ v,
                             float* __restrict__ out, int rows, int cols)
{
    int j = blockIdx.x * 4 + (threadIdx.x >> 6);
    if (j >= cols) return;
    int lane = threadIdx.x & 63;
    float acc = 0.f;
    for (int i = lane; i < rows; i += 64) acc += v[i] * W[(size_t)i * cols + j];
    #pragma unroll
    for (int off = 32; off > 0; off >>= 1) acc += __shfl_down(acc, off);
    if (lane == 0) out[j] = acc;
}

// ---------------- edge_attr column sums -> per-block partials (no atomics) ----------------
__global__ __launch_bounds__(256) void ea_sum_kernel(const float* __restrict__ ea,
                                                     float* __restrict__ partials, int E)
{
    __shared__ float ws[4][16];
    int tid = threadIdx.x;
    int lane = tid & 63, w = tid >> 6;
    float acc[16];
    #pragma unroll
    for (int f = 0; f < 16; f++) acc[f] = 0.f;
    for (int e = blockIdx.x * blockDim.x + tid; e < E; e += gridDim.x * blockDim.x) {
        const float4* p = (const float4*)(ea + (size_t)e * 16);
        float4 v0 = p[0], v1 = p[1], v2 = p[2], v3 = p[3];
        acc[0] += v0.x; acc[1] += v0.y; acc[2] += v0.z; acc[3] += v0.w;
        acc[4] += v1.x; acc[5] += v1.y; acc[6] += v1.z; acc[7] += v1.w;
        acc[8] += v2.x; acc[9] += v2.y; acc[10] += v2.z; acc[11] += v2.w;
        acc[12] += v3.x; acc[13] += v3.y; acc[14] += v3.z; acc[15] += v3.w;
    }
    #pragma unroll
    for (int off = 32; off > 0; off >>= 1)
        #pragma unroll
        for (int f = 0; f < 16; f++) acc[f] += __shfl_down(acc[f], off);
    if (lane == 0)
        #pragma unroll
        for (int f = 0; f < 16; f++) ws[w][f] = acc[f];
    __syncthreads();
    if (tid < 16)
        partials[blockIdx.x * 16 + tid] = ws[0][tid] + ws[1][tid] + ws[2][tid] + ws[3][tid];
}

// aloop = invE * sum_{b,f} partials[b*16+f] * ve[f] — 256-thread parallel reduce
__global__ void finalize_aloop(const float* __restrict__ partials, const float* __restrict__ ve,
                               float* __restrict__ aloop, float invE, int nblk)
{
    int tid = threadIdx.x;
    int total = nblk * 16;
    float vf = ve[tid & 15];          // stride 256 preserves (i & 15)
    float s = 0.f;
    for (int i = tid; i < total; i += 256) s += partials[i] * vf;
    #pragma unroll
    for (int off = 32; off > 0; off >>= 1) s += __shfl_down(s, off);
    __shared__ float ws[4];
    if ((tid & 63) == 0) ws[tid >> 6] = s;
    __syncthreads();
    if (tid == 0) *aloop = (ws[0] + ws[1] + ws[2] + ws[3]) * invE;
}

// ---------------- per-row dots on fp16 matrix (1-2 vectors) ----------------
__global__ void row_dots_h(const f16* __restrict__ Mat, int M,
                           const float* __restrict__ v1, float* __restrict__ o1,
                           const float* __restrict__ v2, float* __restrict__ o2,
                           const float* __restrict__ bias)
{
    int row = blockIdx.x * 4 + (threadIdx.x >> 6);
    if (row >= M) return;
    int lane = threadIdx.x & 63;
    const f16* rp = Mat + (size_t)row * 192;
    float a1 = 0.f, a2 = 0.f;
    #pragma unroll
    for (int k = 0; k < 3; k++) {
        int f = lane + 64 * k;
        float x = (float)rp[f];
        a1 += x * v1[f];
        if (o2) a2 += x * v2[f];
    }
    #pragma unroll
    for (int off = 32; off > 0; off >>= 1) {
        a1 += __shfl_down(a1, off);
        a2 += __shfl_down(a2, off);
    }
    if (lane == 0) {
        o1[row] = a1 + (bias ? bias[0] : 0.f);
        if (o2) o2[row] = a2;
    }
}

// ---------------- alpha + segment max ----------------
__global__ void edge_alpha_max(const int* __restrict__ srcp, const int* __restrict__ dstp,
                               int E_real, int Etot,
                               const float* __restrict__ as_, const float* __restrict__ ad_,
                               const float* __restrict__ ea, const float* __restrict__ ve,
                               const float* __restrict__ aloop, float slope,
                               float* __restrict__ ab, unsigned* __restrict__ mb)
{
    int i = blockIdx.x * blockDim.x + threadIdx.x;
    if (i >= Etot) return;
    int s_, d_;
    float aext = 0.f;
    if (i < E_real) {
        s_ = srcp ? srcp[i] : i;
        d_ = dstp[i];
        if (ea) {
            const float4* p = (const float4*)(ea + (size_t)i * 16);
            const float4* q = (const float4*)ve;
            float4 e0 = p[0], e1 = p[1], e2 = p[2], e3 = p[3];
            float4 w0 = q[0], w1 = q[1], w2 = q[2], w3 = q[3];
            aext = e0.x * w0.x + e0.y * w0.y + e0.z * w0.z + e0.w * w0.w
                 + e1.x * w1.x + e1.y * w1.y + e1.z * w1.z + e1.w * w1.w
                 + e2.x * w2.x + e2.y * w2.y + e2.z * w2.z + e2.w * w2.w
                 + e3.x * w3.x + e3.y * w3.y + e3.z * w3.z + e3.w * w3.w;
        }
    } else {
        s_ = d_ = i - E_real;
        aext = *aloop;
    }
    float a = as_[s_] + ad_[d_] + aext;
    a = a >= 0.f ? a : slope * a;
    ab[i] = a;
    atomicMax(&mb[d_], fmap(a));
}

// ---------------- CSR aggregate with FUSED softmax: Hout16[dst] = elu(sum_e exp(a_e-m)*F[src_e]
//                  / (sum_e exp(a_e-m) + 1e-16) + bias), fp16 out ----------------
// R10: exp + denominator folded in (edge_exp_sum kernel deleted). ab holds RAW alpha;
// mb holds the fmap'ed per-dst max. All lanes iterate the same edges via broadcast, so
// wsum is computed redundantly per lane (no reduction needed). 8-wide unrolled gather.
__global__ __launch_bounds__(256) void csr_aggregate(const int* __restrict__ rowptr,
                                                     const int* __restrict__ csr_src,
                                                     const int* __restrict__ csr_eid,
                                                     int Ndst, int nF, int nAb,
                                                     int selfloop, int selfAb,
                                                     const float* __restrict__ ab,
                                                     const unsigned* __restrict__ mb,
                                                     const f16* __restrict__ F,
                                                     const float* __restrict__ bias,
                                                     f16* __restrict__ Hout16)
{
    int node = blockIdx.x * 4 + (threadIdx.x >> 6);
    if (node >= Ndst) return;
    int lane = threadIdx.x & 63;
    int start = rowptr[node];
    int deg = rowptr[node + 1] - start;
    deg = min(max(deg, 0), 1 << 20);
    float m = funmap(mb[node]);

    float acc0 = 0.f, acc1 = 0.f, acc2 = 0.f, wsum = 0.f;
    for (int base = 0; base < deg; base += 64) {
        int i = base + lane;
        float wv = 0.f;
        int s = 0;
        if (i < deg) {
            int pos = start + i;
            s = csr_src ? csr_src[pos] : pos;
            if ((unsigned)s >= (unsigned)nF) s = 0;
            unsigned eid = csr_eid ? (unsigned)csr_eid[pos] : (unsigned)pos;
            if (eid >= (unsigned)nAb) eid = 0;
            wv = fast_exp(ab[eid] - m);
        }
        int cnt = min(64, deg - base);
        int j = 0;
        for (; j + 8 <= cnt; j += 8) {
            float wj[8];
            const f16* fp[8];
            #pragma unroll
            for (int q = 0; q < 8; q++) {
                wj[q] = __shfl(wv, j + q);
                fp[q] = F + (size_t)__shfl(s, j + q) * 192;
            }
            float a0[8], a1[8], a2[8];
            #pragma unroll
            for (int q = 0; q < 8; q++) {
                a0[q] = (float)fp[q][lane];
                a1[q] = (float)fp[q][lane + 64];
                a2[q] = (float)fp[q][lane + 128];
            }
            #pragma unroll
            for (int q = 0; q < 8; q++) {
                wsum += wj[q];
                acc0 += wj[q] * a0[q];
                acc1 += wj[q] * a1[q];
                acc2 += wj[q] * a2[q];
            }
        }
        for (; j < cnt; j++) {
            float wj = __shfl(wv, j);
            int   sj = __shfl(s, j);
            const f16* fr = F + (size_t)sj * 192;
            wsum += wj;
            acc0 += wj * (float)fr[lane];
            acc1 += wj * (float)fr[lane + 64];
            acc2 += wj * (float)fr[lane + 128];
        }
    }
    if (selfloop) {
        unsigned eid = (unsigned)(selfAb + node);
        float wv = (eid < (unsigned)nAb) ? fast_exp(ab[eid] - m) : 0.f;
        int s = min(node, nF - 1);
        const f16* fr = F + (size_t)s * 192;
        wsum += wv;
        acc0 += wv * (float)fr[lane];
        acc1 += wv * (float)fr[lane + 64];
        acc2 += wv * (float)fr[lane + 128];
    }
    float inv = 1.f / (wsum + 1e-16f);
    float h0 = acc0 * inv + bias[lane];
    float h1 = acc1 * inv + bias[lane + 64];
    float h2 = acc2 * inv + bias[lane + 128];
    f16* orow = Hout16 + (size_t)node * 192;
    orow[lane]       = (f16)(h0 > 0.f ? h0 : fast_expm1(h0));
    orow[lane + 64]  = (f16)(h1 > 0.f ? h1 : fast_expm1(h1));
    orow[lane + 128] = (f16)(h2 > 0.f ? h2 : fast_expm1(h2));
}

// ---------------- pool: per-graph wave sum over contiguous node range, relu, fp16 ----------------
__global__ void pool_csr(const int* __restrict__ brow, const f16* __restrict__ X,
                         f16* __restrict__ outg16, int G)
{
    int g = blockIdx.x * 4 + (threadIdx.x >> 6);
    if (g >= G) return;
    int lane = threadIdx.x & 63;
    float a0 = 0.f, a1 = 0.f, a2 = 0.f;
    int s = max(brow[g], 0);
    int e = min(brow[g + 1], NN);
    for (int n = s; n < e; n++) {
        const f16* xr = X + (size_t)n * 192;
        a0 += (float)xr[lane];
        a1 += (float)xr[lane + 64];
        a2 += (float)xr[lane + 128];
    }
    f16* o = outg16 + (size_t)g * 192;
    o[lane]       = (f16)(a0 > 0.f ? a0 : 0.f);
    o[lane + 64]  = (f16)(a1 > 0.f ? a1 : 0.f);
    o[lane + 128] = (f16)(a2 > 0.f ? a2 : 0.f);
}

// ---------------- launch ----------------
extern "C" void kernel_launch(void* const* d_in, const int* in_sizes, int n_in,
                              void* d_out, int out_size, void* d_ws, size_t ws_size,
                              hipStream_t stream)
{
    const float* x_in        = (const float*)d_in[0];
    const int*   ei          = (const int*)  d_in[1];
    const float* eattr       = (const float*)d_in[2];
    const int*   batch       = (const int*)  d_in[3];
    const float* lin1_W      = (const float*)d_in[4];
    const float* lin1_b      = (const float*)d_in[5];
    const float* conv0_W     = (const float*)d_in[6];
    const float* conv0_att_s = (const float*)d_in[7];
    const float* conv0_att_d = (const float*)d_in[8];
    const float* conv0_We    = (const float*)d_in[9];
    const float* conv0_att_e = (const float*)d_in[10];
    const float* conv0_b     = (const float*)d_in[11];
    const float* convs_W     = (const float*)d_in[12];
    const float* convs_att_s = (const float*)d_in[13];
    const float* convs_att_d = (const float*)d_in[14];
    const float* convs_b     = (const float*)d_in[15];
    const float* gru_Wih     = (const float*)d_in[16];
    const float* gru_Whh     = (const float*)d_in[17];
    const float* gru_bih     = (const float*)d_in[18];
    const float* gru_bhh     = (const float*)d_in[19];
    const float* mol_Wsrc    = (const float*)d_in[20];
    const float* mol_Wdst    = (const float*)d_in[21];
    const float* mol_att_s   = (const float*)d_in[22];
    const float* mol_att_d   = (const float*)d_in[23];
    const float* mol_b       = (const float*)d_in[24];
    const float* mgru_Wih    = (const float*)d_in[25];
    const float* mgru_Whh    = (const float*)d_in[26];
    const float* mgru_bih    = (const float*)d_in[27];
    const float* mgru_bhh    = (const float*)d_in[28];
    const float* lin2_W      = (const float*)d_in[29];
    const float* lin2_b      = (const float*)d_in[30];

    const int* src = ei;
    const int* dst = ei + EE;

    // ---- workspace layout ----
    char* base = (char*)d_ws;
    size_t off = 0;
    auto alloc = [&](size_t bytes) -> void* {
        void* p = base + off;
        off = (off + bytes + 63) & ~(size_t)63;
        return p;
    };
    f16*      w16    = (f16*)alloc((size_t)NN * HH * 2);
    f16*      h16    = (f16*)alloc((size_t)NN * HH * 2);
    f16*      x16    = (f16*)alloc((size_t)NN * HH * 2);
    f16*      x16b   = (f16*)alloc((size_t)NN * HH * 2);   // gru4 ping-pong
    f16*      xin16  = (f16*)alloc((size_t)NN * CIN * 2);
    float*    abuf   = (float*)alloc((size_t)(EE + NN) * 4);
    float*    asb    = (float*)alloc((size_t)NN * 4);
    float*    adb    = (float*)alloc((size_t)NN * 4);
    unsigned* mb     = (unsigned*)alloc((size_t)NN * 4);
    f16*      hg16   = (f16*)alloc((size_t)GG * HH * 2);
    f16*      outg16 = (f16*)alloc((size_t)GG * HH * 2);
    float*    adg    = (float*)alloc((size_t)GG * 4);
    unsigned* mg     = (unsigned*)alloc((size_t)GG * 4);
    int*      degb   = (int*)alloc((size_t)NN * 4);
    int*      rowptr = (int*)alloc((size_t)(NN + 1) * 4);
    unsigned* cursor = (unsigned*)alloc((size_t)NN * 4);
    int*      csr_src = (int*)alloc((size_t)EE * 4);
    int*      csr_eid = (int*)alloc((size_t)EE * 4);
    int*      bdeg   = (int*)alloc((size_t)GG * 4);
    int*      brow   = (int*)alloc((size_t)(GG + 1) * 4);
    int*      csum   = (int*)alloc(64 * 4);
    int*      choff  = (int*)alloc(65 * 4);
    float*    ve     = (float*)alloc(64);
    float*    eapart = (float*)alloc((size_t)EA_BLOCKS * 16 * 4);
    float*    vd     = (float*)alloc(HH * 4);
    float*    aloop  = (float*)alloc(64);
    f16*      lin1W16   = (f16*)alloc((size_t)HH * CIN * 2);
    f16*      conv0W16  = (f16*)alloc((size_t)HH * HH * 2);
    f16*      convsW16  = (f16*)alloc((size_t)2 * HH * HH * 2);
    f16*      gruWih16  = (f16*)alloc((size_t)3 * H3 * HH * 2);
    f16*      gruWhh16  = (f16*)alloc((size_t)3 * H3 * HH * 2);
    f16*      molWs16   = (f16*)alloc((size_t)HH * HH * 2);
    f16*      mgruWih16 = (f16*)alloc((size_t)H3 * HH * 2);
    f16*      mgruWhh16 = (f16*)alloc((size_t)H3 * HH * 2);
    // fragment-packed GRU weights (legacy layout; mol GRU uses slots 6,7)
    f16*      gruWihP   = (f16*)alloc((size_t)3 * FRAG_ELEMS * 8 * 2);
    f16*      gruWhhP   = (f16*)alloc((size_t)3 * FRAG_ELEMS * 8 * 2);
    f16*      mgruWihP  = (f16*)alloc((size_t)FRAG_ELEMS * 8 * 2);
    f16*      mgruWhhP  = (f16*)alloc((size_t)FRAG_ELEMS * 8 * 2);
    // gru4 combined (pass,chunk)-contiguous node-GRU weights: 3 layers x 442 KB
    f16*      gru4W     = (f16*)alloc((size_t)3 * G4_WLAYER * 2);
    if (off > ws_size) return;

    // ---- weight + input converts ----
    cvt_f2h<<<(NN * CIN + 255) / 256, 256, 0, stream>>>(x_in, xin16, NN * CIN);
    Cvt8 cv;
    cv.s[0] = lin1_W;   cv.d[0] = lin1W16;   cv.n[0] = HH * CIN;
    cv.s[1] = conv0_W;  cv.d[1] = conv0W16;  cv.n[1] = HH * HH;
    cv.s[2] = convs_W;  cv.d[2] = convsW16;  cv.n[2] = 2 * HH * HH;
    cv.s[3] = gru_Wih;  cv.d[3] = gruWih16;  cv.n[3] = 3 * H3 * HH;
    cv.s[4] = gru_Whh;  cv.d[4] = gruWhh16;  cv.n[4] = 3 * H3 * HH;
    cv.s[5] = mol_Wsrc; cv.d[5] = molWs16;   cv.n[5] = HH * HH;
    cv.s[6] = mgru_Wih; cv.d[6] = mgruWih16; cv.n[6] = H3 * HH;
    cv.s[7] = mgru_Whh; cv.d[7] = mgruWhh16; cv.n[7] = H3 * HH;
    cvt_multi<<<dim3((3 * H3 * HH + 255) / 256, 8), 256, 0, stream>>>(cv);

    // ---- pack mol GRU weights into legacy fragment-major layout ----
    Pack8 pk;
    const size_t WM = (size_t)H3 * HH;             // 110592 halves per matrix
    pk.s[0] = gruWih16;            pk.d[0] = gruWihP;
    pk.s[1] = gruWih16 + WM;       pk.d[1] = gruWihP + WM;
    pk.s[2] = gruWih16 + 2 * WM;   pk.d[2] = gruWihP + 2 * WM;
    pk.s[3] = gruWhh16;            pk.d[3] = gruWhhP;
    pk.s[4] = gruWhh16 + WM;       pk.d[4] = gruWhhP + WM;
    pk.s[5] = gruWhh16 + 2 * WM;   pk.d[5] = gruWhhP + 2 * WM;
    pk.s[6] = mgruWih16;           pk.d[6] = mgruWihP;
    pk.s[7] = mgruWhh16;           pk.d[7] = mgruWhhP;
    pack_frag<<<dim3((FRAG_ELEMS + 255) / 256, 8), 256, 0, stream>>>(pk);

    // ---- pack node GRU weights into gru4 (pass,chunk)-contiguous layout ----
    pack4<<<dim3(108, 3), 256, 0, stream>>>(gruWih16, gruWhh16, gru4W);

    // ---- CSR build ----
    const int nchunks = (NN + 1023) / 1024;   // 49
    hipMemsetAsync(degb, 0, NN * sizeof(int), stream);
    hist_kernel<<<(EE + 255) / 256, 256, 0, stream>>>(dst, degb, EE, NN);
    chunk_sum<<<nchunks, 256, 0, stream>>>(degb, csum, NN);
    scan_wave<<<1, 64, 0, stream>>>(csum, choff, nullptr, nchunks);
    local_scan<<<nchunks, 256, 0, stream>>>(degb, choff, rowptr, cursor, NN, nchunks);
    scatter_kernel<<<(EE + 255) / 256, 256, 0, stream>>>(src, dst, cursor, csr_src, csr_eid, EE);
    // batch scan (GG=2048): hierarchical (csum/choff reused sequentially on-stream)
    hipMemsetAsync(bdeg, 0, GG * sizeof(int), stream);
    hist_kernel<<<(NN + 255) / 256, 256, 0, stream>>>(batch, bdeg, NN, GG);
    chunk_sum<<<2, 256, 0, stream>>>(bdeg, csum, GG);
    scan_wave<<<1, 64, 0, stream>>>(csum, choff, nullptr, 2);
    local_scan<<<2, 256, 0, stream>>>(bdeg, choff, brow, nullptr, GG, 2);

    // ---- conv0 prep ----
    compose_vec2<<<(EDIM + 3) / 4, 256, 0, stream>>>(conv0_We, conv0_att_e, ve, HH, EDIM);
    ea_sum_kernel<<<EA_BLOCKS, 256, 0, stream>>>(eattr, eapart, EE);
    finalize_aloop<<<1, 256, 0, stream>>>(eapart, ve, aloop, 1.0f / EE, EA_BLOCKS);

    const dim3 gemmGrid((NN + 63) / 64, HH / 64);
    const int g4grid = (NN + G4_ROWS - 1) / G4_ROWS;   // 391

    // ping-pong node feature buffers (gru4 cannot write in place)
    f16* xcur = x16;
    f16* xnxt = x16b;

    // ---- lin1 ----
    gemm_mfma<<<gemmGrid, 256, 0, stream>>>(xin16, lin1W16, lin1_b, nullptr, xcur, NN, HH, CIN, 1);

    // ---- conv0 (edge feats + self loops, slope 0.2) ----
    gemm_mfma<<<gemmGrid, 256, 0, stream>>>(xcur, conv0W16, nullptr, nullptr, w16, NN, HH, HH, 0);
    row_dots_h<<<(NN + 3) / 4, 256, 0, stream>>>(w16, NN, conv0_att_s, asb, conv0_att_d, adb, nullptr);
    hipMemsetAsync(mb, 0, NN * 4, stream);
    edge_alpha_max<<<(EE + NN + 255) / 256, 256, 0, stream>>>(src, dst, EE, EE + NN, asb, adb,
                                                              eattr, ve, aloop, 0.2f, abuf, mb);
    csr_aggregate<<<(NN + 3) / 4, 256, 0, stream>>>(rowptr, csr_src, csr_eid, NN, NN, EE + NN,
                                                    1, EE, abuf, mb, w16, conv0_b, h16);
    gru4_mfma<<<g4grid, 256, 0, stream>>>(h16, xcur, xnxt, gru4W, gru_bih, gru_bhh, NN);
    { f16* tmp = xcur; xcur = xnxt; xnxt = tmp; }

    // ---- remaining atom convs (no self loops, slope 0.01) ----
    for (int l = 0; l < 2; l++) {
        gemm_mfma<<<gemmGrid, 256, 0, stream>>>(xcur, convsW16 + (size_t)l * HH * HH,
                                                nullptr, nullptr, w16, NN, HH, HH, 0);
        row_dots_h<<<(NN + 3) / 4, 256, 0, stream>>>(w16, NN, convs_att_s + l * HH, asb,
                                                     convs_att_d + l * HH, adb, nullptr);
        hipMemsetAsync(mb, 0, NN * 4, stream);
        edge_alpha_max<<<(EE + 255) / 256, 256, 0, stream>>>(src, dst, EE, EE, asb, adb,
                                                             nullptr, nullptr, nullptr, 0.01f, abuf, mb);
        csr_aggregate<<<(NN + 3) / 4, 256, 0, stream>>>(rowptr, csr_src, csr_eid, NN, NN, EE,
                                                        0, 0, abuf, mb, w16, convs_b + l * HH, h16);
        gru4_mfma<<<g4grid, 256, 0, stream>>>(h16, xcur, xnxt,
                                              gru4W + (size_t)(l + 1) * G4_WLAYER,
                                              gru_bih + (size_t)(l + 1) * H3,
                                              gru_bhh + (size_t)(l + 1) * H3, NN);
        { f16* tmp = xcur; xcur = xnxt; xnxt = tmp; }
    }

    // ---- molecule readout ----
    pool_csr<<<(GG + 3) / 4, 256, 0, stream>>>(brow, xcur, outg16, GG);
    gemm_mfma<<<gemmGrid, 256, 0, stream>>>(xcur, molWs16, nullptr, nullptr, w16, NN, HH, HH, 0);
    row_dots_h<<<(NN + 3) / 4, 256, 0, stream>>>(w16, NN, mol_att_s, asb, nullptr, nullptr, nullptr);
    compose_vec2<<<(HH + 3) / 4, 256, 0, stream>>>(mol_Wdst, mol_att_d, vd, HH, HH);

    for (int t = 0; t < 2; t++) {
        row_dots_h<<<(GG + 3) / 4, 256, 0, stream>>>(outg16, GG, vd, adg, nullptr, nullptr, nullptr);
        hipMemsetAsync(mg, 0, GG * 4, stream);
        edge_alpha_max<<<(NN + 255) / 256, 256, 0, stream>>>(nullptr, batch, NN, NN, asb, adg,
                                                             nullptr, nullptr, nullptr, 0.01f, abuf, mg);
        csr_aggregate<<<(GG + 3) / 4, 256, 0, stream>>>(brow, nullptr, nullptr, GG, NN, NN,
                                                        0, 0, abuf, mg, w16, mol_b, hg16);
        gru_mfma<<<(GG + 31) / 32, 256, 0, stream>>>(hg16, outg16, mgruWihP, mgruWhhP,
                                                     mgru_bih, mgru_bhh, GG);
    }

    // ---- final linear ----
    row_dots_h<<<(GG + 3) / 4, 256, 0, stream>>>(outg16, GG, lin2_W, (float*)d_out,
                                                 nullptr, nullptr, lin2_b);
}

// Round 11
// 905.862 us; speedup vs baseline: 2.3022x; 1.1637x over previous
//
#include <hip/hip_runtime.h>
#include <math.h>

// ---------------- problem constants ----------------
#define NN    50000
#define EE    800000
#define CIN   64
#define HH    192
#define EDIM  16
#define GG    2048
#define H3    576   // 3*H
#define EA_BLOCKS 256
#define FRAG_ELEMS (36 * 6 * 64)   // col-blocks * chunks * lanes, per 576x192 matrix
#define G4_WLAYER 221184           // halves per combined gru4 weight layer (2*576*192)

typedef _Float16 f16;
typedef _Float16 half8 __attribute__((ext_vector_type(8)));
typedef float f32x4 __attribute__((ext_vector_type(4)));

// ---------------- helpers ----------------
// fast transcendentals via v_exp_f32 / v_rcp_f32 (~1 ulp; fp16 storage dominates error)
__device__ __forceinline__ float fast_exp(float x) {
    return __builtin_amdgcn_exp2f(1.442695041f * x);
}
__device__ __forceinline__ float fast_sig(float x) {
    return __builtin_amdgcn_rcpf(1.f + __builtin_amdgcn_exp2f(-1.442695041f * x));
}
__device__ __forceinline__ float fast_tanh(float x) {
    return 1.f - 2.f * __builtin_amdgcn_rcpf(1.f + __builtin_amdgcn_exp2f(2.885390082f * x));
}
__device__ __forceinline__ float fast_expm1(float x) {
    return __builtin_amdgcn_exp2f(1.442695041f * x) - 1.f;
}

// async global->LDS, 16 B per lane; LDS dest = wave-uniform base + lane*16
__device__ __forceinline__ void gload_lds16(const f16* g, f16* l) {
    __builtin_amdgcn_global_load_lds(
        (const __attribute__((address_space(1))) unsigned int*)g,
        (__attribute__((address_space(3))) unsigned int*)l,
        16, 0, 0);
}

// ---------------- fp32 -> fp16 converts ----------------
__global__ void cvt_f2h(const float* __restrict__ s, f16* __restrict__ d, int n)
{
    int i = blockIdx.x * blockDim.x + threadIdx.x;
    if (i < n) d[i] = (f16)s[i];
}

struct Cvt8 { const float* s[8]; f16* d[8]; int n[8]; };
__global__ void cvt_multi(Cvt8 c)
{
    int slot = blockIdx.y;
    int i = blockIdx.x * blockDim.x + threadIdx.x;
    if (i < c.n[slot]) c.d[slot][i] = (f16)c.s[slot][i];
}

// ---------------- GRU weight repack: fragment-major for coalesced B-loads (mol GRU) ----------
struct Pack8 { const f16* s[8]; f16* d[8]; };
__global__ __launch_bounds__(256) void pack_frag(Pack8 p)
{
    int slot = blockIdx.y;
    int idx = blockIdx.x * 256 + threadIdx.x;
    if (idx >= FRAG_ELEMS) return;
    int cb   = idx / 384;          // 6*64
    int rem  = idx % 384;
    int c    = rem / 64;
    int lane = rem % 64;
    int col = cb * 16 + (lane & 15);
    int k   = c * 32 + (lane >> 4) * 8;
    *(half8*)(p.d[slot] + (size_t)idx * 8) =
        *(const half8*)(p.s[slot] + (size_t)col * 192 + k);
}

// ---------------- gru4 weight repack: (pass,chunk)-contiguous for global_load_lds staging ----
__global__ __launch_bounds__(256) void pack4(const f16* __restrict__ Wih,
                                             const f16* __restrict__ Whh,
                                             f16* __restrict__ out)
{
    int layer = blockIdx.y;
    int idx = blockIdx.x * 256 + threadIdx.x;          // [0, 432*64)
    if (idx >= 27648) return;
    int frag = idx >> 6, lane = idx & 63;
    int pc6 = frag / 24, r24 = frag % 24;
    int p = pc6 / 6, c = pc6 % 6;
    int m = r24 / 12, g = (r24 % 12) >> 2, cb = r24 & 3;
    const f16* srcm = (m == 0 ? Wih : Whh) + (size_t)layer * (H3 * HH);
    int col = g * 192 + p * 64 + cb * 16 + (lane & 15);
    int k   = c * 32 + (lane >> 4) * 8;
    *(half8*)(out + (size_t)layer * G4_WLAYER + (size_t)idx * 8) =
        *(const half8*)(srcm + (size_t)col * 192 + k);
}

// ---------------- CSR build ----------------
__global__ void hist_kernel(const int* __restrict__ idx, int* __restrict__ deg, int n, int nbins)
{
    int i = blockIdx.x * blockDim.x + threadIdx.x;
    if (i < n) {
        unsigned b = (unsigned)idx[i];
        if (b < (unsigned)nbins) atomicAdd(&deg[b], 1);
    }
}

// single-WAVE exclusive scan (serial over 64-chunks) — small arrays only
__global__ void scan_wave(const int* __restrict__ deg, int* __restrict__ rowptr,
                          unsigned* __restrict__ cursor, int n)
{
    int lane = threadIdx.x & 63;
    int carry = 0;
    for (int base = 0; base < n; base += 64) {
        int i = base + lane;
        int v = (i < n) ? deg[i] : 0;
        int x = v;
        #pragma unroll
        for (int off = 1; off < 64; off <<= 1) {
            int t = __shfl_up(x, off);
            if (lane >= off) x += t;
        }
        int ex = carry + x - v;
        if (i < n) {
            rowptr[i] = ex;
            if (cursor) cursor[i] = (unsigned)ex;
        }
        carry += __shfl(x, 63);
    }
    if (lane == 0) rowptr[n] = carry;
}

// hierarchical scan, level 1: per-1024-chunk sums
__global__ __launch_bounds__(256) void chunk_sum(const int* __restrict__ deg,
                                                 int* __restrict__ csum, int n)
{
    int base = blockIdx.x * 1024;
    int tid = threadIdx.x;
    int i0 = base + tid * 4;
    int s = 0;
    #pragma unroll
    for (int k = 0; k < 4; k++) { int i = i0 + k; if (i < n) s += deg[i]; }
    #pragma unroll
    for (int off = 32; off > 0; off >>= 1) s += __shfl_down(s, off);
    __shared__ int ws[4];
    int lane = tid & 63, w = tid >> 6;
    if (lane == 0) ws[w] = s;
    __syncthreads();
    if (tid == 0) csum[blockIdx.x] = ws[0] + ws[1] + ws[2] + ws[3];
}

// hierarchical scan, level 3: local exclusive scan + chunk offset
__global__ __launch_bounds__(256) void local_scan(const int* __restrict__ deg,
                                                  const int* __restrict__ choff,
                                                  int* __restrict__ rowptr,
                                                  unsigned* __restrict__ cursor,
                                                  int n, int nchunks)
{
    int base = blockIdx.x * 1024;
    int tid = threadIdx.x;
    int lane = tid & 63, w = tid >> 6;
    int i0 = base + tid * 4;
    int v[4];
    #pragma unroll
    for (int k = 0; k < 4; k++) { int i = i0 + k; v[k] = (i < n) ? deg[i] : 0; }
    int tsum = v[0] + v[1] + v[2] + v[3];
    int x = tsum;
    #pragma unroll
    for (int off = 1; off < 64; off <<= 1) {
        int t = __shfl_up(x, off);
        if (lane >= off) x += t;
    }
    __shared__ int wtot[4];
    if (lane == 63) wtot[w] = x;
    __syncthreads();
    int woff = 0;
    #pragma unroll
    for (int j = 0; j < 4; j++) if (j < w) woff += wtot[j];
    int ex = choff[blockIdx.x] + woff + x - tsum;
    #pragma unroll
    for (int k = 0; k < 4; k++) {
        int i = i0 + k;
        if (i < n) {
            rowptr[i] = ex;
            if (cursor) cursor[i] = (unsigned)ex;
        }
        ex += v[k];
    }
    if (blockIdx.x == 0 && tid == 0) rowptr[n] = choff[nchunks];
}

__global__ void scatter_kernel(const int* __restrict__ src, const int* __restrict__ dst,
                               unsigned* __restrict__ cursor,
                               int* __restrict__ csr_src, int* __restrict__ csr_eid, int E)
{
    int e = blockIdx.x * blockDim.x + threadIdx.x;
    if (e >= E) return;
    unsigned d = (unsigned)dst[e];
    if (d >= (unsigned)NN) return;
    unsigned p = atomicAdd(&cursor[d], 1u);
    if (p < (unsigned)E) {
        csr_src[p] = src[e];
        csr_eid[p] = e;
    }
}

// ---------------- MFMA GEMM: C[M,N] = act(A16[M,K] @ W16[N,K]^T + bias) ----------------
__global__ __launch_bounds__(256) void gemm_mfma(const f16* __restrict__ A,
                                                 const f16* __restrict__ W,
                                                 const float* __restrict__ bias,
                                                 float* __restrict__ Cf,
                                                 f16* __restrict__ Ch,
                                                 int M, int N, int K, int act)
{
    __shared__ __align__(16) f16 sA[64 * 40];
    const int tid  = threadIdx.x;
    const int lane = tid & 63;
    const int wid  = tid >> 6;
    const int wy = wid >> 1, wx = wid & 1;
    const int m0 = blockIdx.x << 6, n0 = blockIdx.y << 6;
    const int n_ = lane & 15, quad = lane >> 4;

    f32x4 acc[2][2] = {};
    int boff0 = (n0 + wx * 32 + n_) * K + quad * 8;
    int boff1 = boff0 + 16 * K;

    const int srow = tid >> 2;
    const int skc  = (tid & 3) << 3;

    for (int k0 = 0; k0 < K; k0 += 32) {
        half8 av = {};
        int gm = m0 + srow;
        if (gm < M) av = *(const half8*)(A + (size_t)gm * K + k0 + skc);
        *(half8*)(sA + srow * 40 + skc) = av;
        __syncthreads();
        half8 a0 = *(const half8*)(sA + (wy * 32 + n_) * 40 + quad * 8);
        half8 a1 = *(const half8*)(sA + (wy * 32 + 16 + n_) * 40 + quad * 8);
        half8 b0 = *(const half8*)(W + boff0 + k0);
        half8 b1 = *(const half8*)(W + boff1 + k0);
        acc[0][0] = __builtin_amdgcn_mfma_f32_16x16x32_f16(a0, b0, acc[0][0], 0, 0, 0);
        acc[0][1] = __builtin_amdgcn_mfma_f32_16x16x32_f16(a0, b1, acc[0][1], 0, 0, 0);
        acc[1][0] = __builtin_amdgcn_mfma_f32_16x16x32_f16(a1, b0, acc[1][0], 0, 0, 0);
        acc[1][1] = __builtin_amdgcn_mfma_f32_16x16x32_f16(a1, b1, acc[1][1], 0, 0, 0);
        __syncthreads();
    }
    #pragma unroll
    for (int i = 0; i < 2; i++)
        #pragma unroll
        for (int j = 0; j < 2; j++) {
            int col = n0 + wx * 32 + j * 16 + n_;
            float bv = bias ? bias[col] : 0.f;
            #pragma unroll
            for (int reg = 0; reg < 4; reg++) {
                int row = m0 + wy * 32 + i * 16 + quad * 4 + reg;
                if (row >= M) continue;
                float v = acc[i][j][reg] + bv;
                if (act == 1) v = v >= 0.f ? v : 0.01f * v;
                if (Cf) Cf[(size_t)row * N + col] = v;
                if (Ch) Ch[(size_t)row * N + col] = (f16)v;
            }
        }
}

// ---------------- legacy fused GRU (kept for small M = molecule level) ----------------
#define GRU_LDP 208
__global__ __launch_bounds__(256, 2) void gru_mfma(const f16* __restrict__ H16,
                                                   f16* __restrict__ X16,
                                                   const f16* __restrict__ Pih,
                                                   const f16* __restrict__ Phh,
                                                   const float* __restrict__ bih,
                                                   const float* __restrict__ bhh,
                                                   int M)
{
    __shared__ __align__(16) f16 sH[32 * GRU_LDP];
    __shared__ __align__(16) f16 sX[32 * GRU_LDP];
    const int tid  = threadIdx.x;
    const int lane = tid & 63;
    const int w    = tid >> 6;
    const int n_ = lane & 15, quad = lane >> 4;
    const int node0 = blockIdx.x << 5;

    {
        const int r  = tid >> 3;
        const int cb = (tid & 7) * 24;
        const int gm = node0 + r;
        if (gm < M) {
            const f16* hp = H16 + (size_t)gm * 192 + cb;
            const f16* xp = X16 + (size_t)gm * 192 + cb;
            #pragma unroll
            for (int q = 0; q < 3; q++) {
                *(half8*)(sH + r * GRU_LDP + cb + q * 8) = *(const half8*)(hp + q * 8);
                *(half8*)(sX + r * GRU_LDP + cb + q * 8) = *(const half8*)(xp + q * 8);
            }
        } else {
            half8 z = {};
            #pragma unroll
            for (int q = 0; q < 3; q++) {
                *(half8*)(sH + r * GRU_LDP + cb + q * 8) = z;
                *(half8*)(sX + r * GRU_LDP + cb + q * 8) = z;
            }
        }
    }
    __syncthreads();

    f32x4 aRZ[2][2][3] = {};
    f32x4 aIN[2][3] = {};
    f32x4 aHN[2][3] = {};
    int fb[3][3];
    #pragma unroll
    for (int g = 0; g < 3; g++)
        #pragma unroll
        for (int t = 0; t < 3; t++)
            fb[g][t] = (g * 12 + w * 3 + t) * 3072 + lane * 8;

    #pragma unroll 1
    for (int c = 0; c < 6; c++) {
        int k0 = c * 32;
        int po = c * 512;
        half8 ah0 = *(const half8*)(sH + n_ * GRU_LDP + k0 + quad * 8);
        half8 ah1 = *(const half8*)(sH + (16 + n_) * GRU_LDP + k0 + quad * 8);
        half8 ax0 = *(const half8*)(sX + n_ * GRU_LDP + k0 + quad * 8);
        half8 ax1 = *(const half8*)(sX + (16 + n_) * GRU_LDP + k0 + quad * 8);
        #pragma unroll
        for (int g = 0; g < 2; g++)
            #pragma unroll
            for (int t = 0; t < 3; t++) {
                half8 bI = *(const half8*)(Pih + fb[g][t] + po);
                half8 bH = *(const half8*)(Phh + fb[g][t] + po);
                aRZ[0][g][t] = __builtin_amdgcn_mfma_f32_16x16x32_f16(ah0, bI, aRZ[0][g][t], 0, 0, 0);
                aRZ[1][g][t] = __builtin_amdgcn_mfma_f32_16x16x32_f16(ah1, bI, aRZ[1][g][t], 0, 0, 0);
                aRZ[0][g][t] = __builtin_amdgcn_mfma_f32_16x16x32_f16(ax0, bH, aRZ[0][g][t], 0, 0, 0);
                aRZ[1][g][t] = __builtin_amdgcn_mfma_f32_16x16x32_f16(ax1, bH, aRZ[1][g][t], 0, 0, 0);
            }
        #pragma unroll
        for (int t = 0; t < 3; t++) {
            half8 bI = *(const half8*)(Pih + fb[2][t] + po);
            half8 bH = *(const half8*)(Phh + fb[2][t] + po);
            aIN[0][t] = __builtin_amdgcn_mfma_f32_16x16x32_f16(ah0, bI, aIN[0][t], 0, 0, 0);
            aIN[1][t] = __builtin_amdgcn_mfma_f32_16x16x32_f16(ah1, bI, aIN[1][t], 0, 0, 0);
            aHN[0][t] = __builtin_amdgcn_mfma_f32_16x16x32_f16(ax0, bH, aHN[0][t], 0, 0, 0);
            aHN[1][t] = __builtin_amdgcn_mfma_f32_16x16x32_f16(ax1, bH, aHN[1][t], 0, 0, 0);
        }
    }

    #pragma unroll
    for (int t = 0; t < 3; t++) {
        const int c0 = w * 48 + t * 16 + n_;
        float brz = bih[c0] + bhh[c0];
        float bzz = bih[c0 + 192] + bhh[c0 + 192];
        float bin = bih[c0 + 384], bhn = bhh[c0 + 384];
        #pragma unroll
        for (int half = 0; half < 2; half++) {
            #pragma unroll
            for (int reg = 0; reg < 4; reg++) {
                int rl = half * 16 + quad * 4 + reg;
                int node = node0 + rl;
                if (node >= M) continue;
                float hx = (float)sX[rl * GRU_LDP + c0];
                float r  = fast_sig(aRZ[half][0][t][reg] + brz);
                float z  = fast_sig(aRZ[half][1][t][reg] + bzz);
                float nn = fast_tanh(aIN[half][t][reg] + bin + r * (aHN[half][t][reg] + bhn));
                float o  = (1.f - z) * nn + z * hx;
                X16[(size_t)node * 192 + c0] = (f16)(o > 0.f ? o : 0.f);
            }
        }
    }
}

// ---------------- gru4: 128 rows/block, 3 sequential 64-col passes, LDS weight pipeline ----
// (R7 schedule: plain __syncthreads per step keeps acc in AGPRs; see R9 post-mortem.)
#define G4_ROWS 128
__global__ __launch_bounds__(256, 2) void gru4_mfma(const f16* __restrict__ H16,
                                                    const f16* __restrict__ Xold,
                                                    f16* __restrict__ Xnew,
                                                    const f16* __restrict__ W4,
                                                    const float* __restrict__ bih,
                                                    const float* __restrict__ bhh,
                                                    int M)
{
    __shared__ __align__(16) f16 sB[2][12288];   // 2 x 24576 B weight chunk buffers
    const int tid  = threadIdx.x;
    const int lane = tid & 63;
    const int w    = tid >> 6;
    const int n_ = lane & 15, quad = lane >> 4;
    const int rb = blockIdx.x * G4_ROWS + w * 32;   // wave's 32 rows
    const int r0 = min(rb + n_,      M - 1);
    const int r1 = min(rb + 16 + n_, M - 1);

    half8 aA[4], aB[4];
    f32x4 acc[2][4][4] = {};   // [row-half][col-block][gate: r,z,in,hn]

#define G4_STAGE(B, PC) do {                                                   \
        const f16* gs_ = W4 + (size_t)(PC) * 12288 + (w * 6) * 512 + lane * 8; \
        f16* ls_ = &sB[B][(w * 6) * 512];                                      \
        _Pragma("unroll")                                                      \
        for (int i_ = 0; i_ < 6; i_++)                                         \
            gload_lds16(gs_ + i_ * 512, ls_ + i_ * 512);                       \
    } while (0)

#define G4_ALOAD(AB, C) do {                                                   \
        const f16* h0_ = H16  + (size_t)r0 * 192 + (C) * 32 + quad * 8;        \
        const f16* h1_ = H16  + (size_t)r1 * 192 + (C) * 32 + quad * 8;        \
        const f16* x0_ = Xold + (size_t)r0 * 192 + (C) * 32 + quad * 8;        \
        const f16* x1_ = Xold + (size_t)r1 * 192 + (C) * 32 + quad * 8;        \
        AB[0] = *(const half8*)h0_;                                            \
        AB[1] = *(const half8*)h1_;                                            \
        AB[2] = *(const half8*)x0_;                                            \
        AB[3] = *(const half8*)x1_;                                            \
    } while (0)

#define G4_COMP(AB, CUR) do {                                                  \
        _Pragma("unroll")                                                      \
        for (int cb_ = 0; cb_ < 4; cb_++) {                                    \
            const f16* bp_ = &sB[CUR][cb_ * 512 + lane * 8];                   \
            half8 rI_ = *(const half8*)(bp_);                                  \
            half8 zI_ = *(const half8*)(bp_ + 2048);                           \
            half8 nI_ = *(const half8*)(bp_ + 4096);                           \
            half8 rH_ = *(const half8*)(bp_ + 6144);                           \
            half8 zH_ = *(const half8*)(bp_ + 8192);                           \
            half8 nH_ = *(const half8*)(bp_ + 10240);                          \
            acc[0][cb_][0] = __builtin_amdgcn_mfma_f32_16x16x32_f16(AB[0], rI_, acc[0][cb_][0], 0, 0, 0); \
            acc[0][cb_][0] = __builtin_amdgcn_mfma_f32_16x16x32_f16(AB[2], rH_, acc[0][cb_][0], 0, 0, 0); \
            acc[1][cb_][0] = __builtin_amdgcn_mfma_f32_16x16x32_f16(AB[1], rI_, acc[1][cb_][0], 0, 0, 0); \
            acc[1][cb_][0] = __builtin_amdgcn_mfma_f32_16x16x32_f16(AB[3], rH_, acc[1][cb_][0], 0, 0, 0); \
            acc[0][cb_][1] = __builtin_amdgcn_mfma_f32_16x16x32_f16(AB[0], zI_, acc[0][cb_][1], 0, 0, 0); \
            acc[0][cb_][1] = __builtin_amdgcn_mfma_f32_16x16x32_f16(AB[2], zH_, acc[0][cb_][1], 0, 0, 0); \
            acc[1][cb_][1] = __builtin_amdgcn_mfma_f32_16x16x32_f16(AB[1], zI_, acc[1][cb_][1], 0, 0, 0); \
            acc[1][cb_][1] = __builtin_amdgcn_mfma_f32_16x16x32_f16(AB[3], zH_, acc[1][cb_][1], 0, 0, 0); \
            acc[0][cb_][2] = __builtin_amdgcn_mfma_f32_16x16x32_f16(AB[0], nI_, acc[0][cb_][2], 0, 0, 0); \
            acc[1][cb_][2] = __builtin_amdgcn_mfma_f32_16x16x32_f16(AB[1], nI_, acc[1][cb_][2], 0, 0, 0); \
            acc[0][cb_][3] = __builtin_amdgcn_mfma_f32_16x16x32_f16(AB[2], nH_, acc[0][cb_][3], 0, 0, 0); \
            acc[1][cb_][3] = __builtin_amdgcn_mfma_f32_16x16x32_f16(AB[3], nH_, acc[1][cb_][3], 0, 0, 0); \
        }                                                                      \
    } while (0)

#define G4_EPI(P) do {                                                         \
        _Pragma("unroll")                                                      \
        for (int cb_ = 0; cb_ < 4; cb_++) {                                    \
            int c0_ = (P) * 64 + cb_ * 16 + n_;                                \
            float brz_ = bih[c0_] + bhh[c0_];                                  \
            float bzz_ = bih[c0_ + 192] + bhh[c0_ + 192];                      \
            float bin_ = bih[c0_ + 384], bhn_ = bhh[c0_ + 384];                \
            _Pragma("unroll")                                                  \
            for (int rh_ = 0; rh_ < 2; rh_++) {                                \
                _Pragma("unroll")                                              \
                for (int rg_ = 0; rg_ < 4; rg_++) {                            \
                    int node_ = rb + rh_ * 16 + quad * 4 + rg_;                \
                    if (node_ < M) {                                           \
                        float hx_ = (float)Xold[(size_t)node_ * 192 + c0_];    \
                        float r_  = fast_sig(acc[rh_][cb_][0][rg_] + brz_);    \
                        float z_  = fast_sig(acc[rh_][cb_][1][rg_] + bzz_);    \
                        float nn_ = fast_tanh(acc[rh_][cb_][2][rg_] + bin_ + r_ * (acc[rh_][cb_][3][rg_] + bhn_)); \
                        float o_  = (1.f - z_) * nn_ + z_ * hx_;               \
                        Xnew[(size_t)node_ * 192 + c0_] = (f16)(o_ > 0.f ? o_ : 0.f); \
                    }                                                          \
                    acc[rh_][cb_][0][rg_] = 0.f;                               \
                    acc[rh_][cb_][1][rg_] = 0.f;                               \
                    acc[rh_][cb_][2][rg_] = 0.f;                               \
                    acc[rh_][cb_][3][rg_] = 0.f;                               \
                }                                                              \
            }                                                                  \
        }                                                                      \
    } while (0)

#define G4_STEP(ACUR, ANXT, PC) do {                                           \
        if ((PC) < 17) {                                                       \
            G4_STAGE(((PC) + 1) & 1, (PC) + 1);                                \
            G4_ALOAD(ANXT, ((PC) + 1) % 6);                                    \
        }                                                                      \
        G4_COMP(ACUR, (PC) & 1);                                               \
        if (((PC) % 6) == 5) G4_EPI((PC) / 6);                                 \
        __syncthreads();                                                       \
    } while (0)

    // prologue: stage chunk 0 + A chunk 0
    G4_STAGE(0, 0);
    G4_ALOAD(aA, 0);
    __syncthreads();

    for (int pc = 0; pc < 18; pc += 2) {
        G4_STEP(aA, aB, pc);
        G4_STEP(aB, aA, pc + 1);
    }

#undef G4_STAGE
#undef G4_ALOAD
#undef G4_COMP
#undef G4_EPI
#undef G4_STEP
}

// ---------------- vector compose: one WAVE per output column (latency-parallel) ----------
__global__ void compose_vec2(const float* __restrict__ W, const float* __restrict__ v,
                             float* __restrict__ out, int rows, int cols)
{
    int j = blockIdx.x * 4 + (threadIdx.x >> 6);
    if (j >= cols) return;
    int lane = threadIdx.x & 63;
    float acc = 0.f;
    for (int i = lane; i < rows; i += 64) acc += v[i] * W[(size_t)i * cols + j];
    #pragma unroll
    for (int off = 32; off > 0; off >>= 1) acc += __shfl_down(acc, off);
    if (lane == 0) out[j] = acc;
}

// ---------------- edge_attr column sums -> per-block partials (no atomics) ----------------
__global__ __launch_bounds__(256) void ea_sum_kernel(const float* __restrict__ ea,
                                                     float* __restrict__ partials, int E)
{
    __shared__ float ws[4][16];
    int tid = threadIdx.x;
    int lane = tid & 63, w = tid >> 6;
    float acc[16];
    #pragma unroll
    for (int f = 0; f < 16; f++) acc[f] = 0.f;
    for (int e = blockIdx.x * blockDim.x + tid; e < E; e += gridDim.x * blockDim.x) {
        const float4* p = (const float4*)(ea + (size_t)e * 16);
        float4 v0 = p[0], v1 = p[1], v2 = p[2], v3 = p[3];
        acc[0] += v0.x; acc[1] += v0.y; acc[2] += v0.z; acc[3] += v0.w;
        acc[4] += v1.x; acc[5] += v1.y; acc[6] += v1.z; acc[7] += v1.w;
        acc[8] += v2.x; acc[9] += v2.y; acc[10] += v2.z; acc[11] += v2.w;
        acc[12] += v3.x; acc[13] += v3.y; acc[14] += v3.z; acc[15] += v3.w;
    }
    #pragma unroll
    for (int off = 32; off > 0; off >>= 1)
        #pragma unroll
        for (int f = 0; f < 16; f++) acc[f] += __shfl_down(acc[f], off);
    if (lane == 0)
        #pragma unroll
        for (int f = 0; f < 16; f++) ws[w][f] = acc[f];
    __syncthreads();
    if (tid < 16)
        partials[blockIdx.x * 16 + tid] = ws[0][tid] + ws[1][tid] + ws[2][tid] + ws[3][tid];
}

// aloop = invE * sum_{b,f} partials[b*16+f] * ve[f] — 256-thread parallel reduce
__global__ void finalize_aloop(const float* __restrict__ partials, const float* __restrict__ ve,
                               float* __restrict__ aloop, float invE, int nblk)
{
    int tid = threadIdx.x;
    int total = nblk * 16;
    float vf = ve[tid & 15];          // stride 256 preserves (i & 15)
    float s = 0.f;
    for (int i = tid; i < total; i += 256) s += partials[i] * vf;
    #pragma unroll
    for (int off = 32; off > 0; off >>= 1) s += __shfl_down(s, off);
    __shared__ float ws[4];
    if ((tid & 63) == 0) ws[tid >> 6] = s;
    __syncthreads();
    if (tid == 0) *aloop = (ws[0] + ws[1] + ws[2] + ws[3]) * invE;
}

// ---------------- per-row dots on fp16 matrix (1-2 vectors) ----------------
__global__ void row_dots_h(const f16* __restrict__ Mat, int M,
                           const float* __restrict__ v1, float* __restrict__ o1,
                           const float* __restrict__ v2, float* __restrict__ o2,
                           const float* __restrict__ bias)
{
    int row = blockIdx.x * 4 + (threadIdx.x >> 6);
    if (row >= M) return;
    int lane = threadIdx.x & 63;
    const f16* rp = Mat + (size_t)row * 192;
    float a1 = 0.f, a2 = 0.f;
    #pragma unroll
    for (int k = 0; k < 3; k++) {
        int f = lane + 64 * k;
        float x = (float)rp[f];
        a1 += x * v1[f];
        if (o2) a2 += x * v2[f];
    }
    #pragma unroll
    for (int off = 32; off > 0; off >>= 1) {
        a1 += __shfl_down(a1, off);
        a2 += __shfl_down(a2, off);
    }
    if (lane == 0) {
        o1[row] = a1 + (bias ? bias[0] : 0.f);
        if (o2) o2[row] = a2;
    }
}

// ---------------- CSR aggregate with FULLY FUSED GAT softmax (online-max, flash style) ----
// R11: edge_alpha_max folded in. Per chunk of 64 edges, each lane computes its edge's raw
// alpha = lrelu(as_[src] + ad_[node] + aext); wave max-reduce -> running max m with
// acc/wsum rescale by exp(m_old - m_new); weights w = exp(a - m). Identical math to
// segment_max -> exp -> sum (mod fp reassociation). Empty segments: no exp evaluated,
// acc=wsum=0 -> output = bias (matches reference's finite-max guard).
__global__ __launch_bounds__(256) void csr_aggregate(const int* __restrict__ rowptr,
                                                     const int* __restrict__ csr_src,
                                                     const int* __restrict__ csr_eid,
                                                     int Ndst, int nF,
                                                     int selfloop, float slope,
                                                     const float* __restrict__ as_,
                                                     const float* __restrict__ ad_,
                                                     const float* __restrict__ ea,
                                                     const float* __restrict__ ve,
                                                     const float* __restrict__ aloop,
                                                     const f16* __restrict__ F,
                                                     const float* __restrict__ bias,
                                                     f16* __restrict__ Hout16)
{
    int node = blockIdx.x * 4 + (threadIdx.x >> 6);
    if (node >= Ndst) return;
    int lane = threadIdx.x & 63;
    int start = rowptr[node];
    int deg = rowptr[node + 1] - start;
    deg = min(max(deg, 0), 1 << 20);
    float adn = ad_[node];

    float m = -INFINITY;
    float acc0 = 0.f, acc1 = 0.f, acc2 = 0.f, wsum = 0.f;
    for (int base = 0; base < deg; base += 64) {
        int i = base + lane;
        float a = -INFINITY;
        int s = 0;
        if (i < deg) {
            int pos = start + i;
            s = csr_src ? csr_src[pos] : pos;
            if ((unsigned)s >= (unsigned)nF) s = 0;
            float aext = 0.f;
            if (ea) {
                unsigned eid = (unsigned)csr_eid[pos];
                if (eid >= (unsigned)EE) eid = 0;
                const float4* p = (const float4*)(ea + (size_t)eid * 16);
                const float4* q = (const float4*)ve;
                float4 e0 = p[0], e1 = p[1], e2 = p[2], e3 = p[3];
                float4 w0 = q[0], w1 = q[1], w2 = q[2], w3 = q[3];
                aext = e0.x * w0.x + e0.y * w0.y + e0.z * w0.z + e0.w * w0.w
                     + e1.x * w1.x + e1.y * w1.y + e1.z * w1.z + e1.w * w1.w
                     + e2.x * w2.x + e2.y * w2.y + e2.z * w2.z + e2.w * w2.w
                     + e3.x * w3.x + e3.y * w3.y + e3.z * w3.z + e3.w * w3.w;
            }
            a = as_[s] + adn + aext;
            a = a >= 0.f ? a : slope * a;
        }
        // wave max + online rescale
        float cm = a;
        #pragma unroll
        for (int off = 32; off > 0; off >>= 1) cm = fmaxf(cm, __shfl_xor(cm, off));
        float mn = fmaxf(m, cm);
        float sc = fast_exp(m - mn);    // m=-inf first chunk -> 0, acc already 0
        acc0 *= sc; acc1 *= sc; acc2 *= sc; wsum *= sc;
        m = mn;
        float wv = fast_exp(a - m);     // inactive lanes: exp(-inf) = 0

        int cnt = min(64, deg - base);
        int j = 0;
        for (; j + 8 <= cnt; j += 8) {
            float wj[8];
            const f16* fp[8];
            #pragma unroll
            for (int q = 0; q < 8; q++) {
                wj[q] = __shfl(wv, j + q);
                fp[q] = F + (size_t)__shfl(s, j + q) * 192;
            }
            float a0[8], a1[8], a2[8];
            #pragma unroll
            for (int q = 0; q < 8; q++) {
                a0[q] = (float)fp[q][lane];
                a1[q] = (float)fp[q][lane + 64];
                a2[q] = (float)fp[q][lane + 128];
            }
            #pragma unroll
            for (int q = 0; q < 8; q++) {
                wsum += wj[q];
                acc0 += wj[q] * a0[q];
                acc1 += wj[q] * a1[q];
                acc2 += wj[q] * a2[q];
            }
        }
        for (; j < cnt; j++) {
            float wj = __shfl(wv, j);
            int   sj = __shfl(s, j);
            const f16* fr = F + (size_t)sj * 192;
            wsum += wj;
            acc0 += wj * (float)fr[lane];
            acc1 += wj * (float)fr[lane + 64];
            acc2 += wj * (float)fr[lane + 128];
        }
    }
    if (selfloop) {
        float a = as_[node] + adn + *aloop;
        a = a >= 0.f ? a : slope * a;
        float mn = fmaxf(m, a);
        float sc = fast_exp(m - mn);
        acc0 *= sc; acc1 *= sc; acc2 *= sc; wsum *= sc;
        float wv = fast_exp(a - mn);
        int s = min(node, nF - 1);
        const f16* fr = F + (size_t)s * 192;
        wsum += wv;
        acc0 += wv * (float)fr[lane];
        acc1 += wv * (float)fr[lane + 64];
        acc2 += wv * (float)fr[lane + 128];
    }
    float inv = 1.f / (wsum + 1e-16f);
    float h0 = acc0 * inv + bias[lane];
    float h1 = acc1 * inv + bias[lane + 64];
    float h2 = acc2 * inv + bias[lane + 128];
    f16* orow = Hout16 + (size_t)node * 192;
    orow[lane]       = (f16)(h0 > 0.f ? h0 : fast_expm1(h0));
    orow[lane + 64]  = (f16)(h1 > 0.f ? h1 : fast_expm1(h1));
    orow[lane + 128] = (f16)(h2 > 0.f ? h2 : fast_expm1(h2));
}

// ---------------- pool: per-graph wave sum over contiguous node range, relu, fp16 ----------------
__global__ void pool_csr(const int* __restrict__ brow, const f16* __restrict__ X,
                         f16* __restrict__ outg16, int G)
{
    int g = blockIdx.x * 4 + (threadIdx.x >> 6);
    if (g >= G) return;
    int lane = threadIdx.x & 63;
    float a0 = 0.f, a1 = 0.f, a2 = 0.f;
    int s = max(brow[g], 0);
    int e = min(brow[g + 1], NN);
    for (int n = s; n < e; n++) {
        const f16* xr = X + (size_t)n * 192;
        a0 += (float)xr[lane];
        a1 += (float)xr[lane + 64];
        a2 += (float)xr[lane + 128];
    }
    f16* o = outg16 + (size_t)g * 192;
    o[lane]       = (f16)(a0 > 0.f ? a0 : 0.f);
    o[lane + 64]  = (f16)(a1 > 0.f ? a1 : 0.f);
    o[lane + 128] = (f16)(a2 > 0.f ? a2 : 0.f);
}

// ---------------- launch ----------------
extern "C" void kernel_launch(void* const* d_in, const int* in_sizes, int n_in,
                              void* d_out, int out_size, void* d_ws, size_t ws_size,
                              hipStream_t stream)
{
    const float* x_in        = (const float*)d_in[0];
    const int*   ei          = (const int*)  d_in[1];
    const float* eattr       = (const float*)d_in[2];
    const int*   batch       = (const int*)  d_in[3];
    const float* lin1_W      = (const float*)d_in[4];
    const float* lin1_b      = (const float*)d_in[5];
    const float* conv0_W     = (const float*)d_in[6];
    const float* conv0_att_s = (const float*)d_in[7];
    const float* conv0_att_d = (const float*)d_in[8];
    const float* conv0_We    = (const float*)d_in[9];
    const float* conv0_att_e = (const float*)d_in[10];
    const float* conv0_b     = (const float*)d_in[11];
    const float* convs_W     = (const float*)d_in[12];
    const float* convs_att_s = (const float*)d_in[13];
    const float* convs_att_d = (const float*)d_in[14];
    const float* convs_b     = (const float*)d_in[15];
    const float* gru_Wih     = (const float*)d_in[16];
    const float* gru_Whh     = (const float*)d_in[17];
    const float* gru_bih     = (const float*)d_in[18];
    const float* gru_bhh     = (const float*)d_in[19];
    const float* mol_Wsrc    = (const float*)d_in[20];
    const float* mol_Wdst    = (const float*)d_in[21];
    const float* mol_att_s   = (const float*)d_in[22];
    const float* mol_att_d   = (const float*)d_in[23];
    const float* mol_b       = (const float*)d_in[24];
    const float* mgru_Wih    = (const float*)d_in[25];
    const float* mgru_Whh    = (const float*)d_in[26];
    const float* mgru_bih    = (const float*)d_in[27];
    const float* mgru_bhh    = (const float*)d_in[28];
    const float* lin2_W      = (const float*)d_in[29];
    const float* lin2_b      = (const float*)d_in[30];

    const int* src = ei;
    const int* dst = ei + EE;

    // ---- workspace layout ----
    char* base = (char*)d_ws;
    size_t off = 0;
    auto alloc = [&](size_t bytes) -> void* {
        void* p = base + off;
        off = (off + bytes + 63) & ~(size_t)63;
        return p;
    };
    f16*      w16    = (f16*)alloc((size_t)NN * HH * 2);
    f16*      h16    = (f16*)alloc((size_t)NN * HH * 2);
    f16*      x16    = (f16*)alloc((size_t)NN * HH * 2);
    f16*      x16b   = (f16*)alloc((size_t)NN * HH * 2);   // gru4 ping-pong
    f16*      xin16  = (f16*)alloc((size_t)NN * CIN * 2);
    float*    asb    = (float*)alloc((size_t)NN * 4);
    float*    adb    = (float*)alloc((size_t)NN * 4);
    f16*      hg16   = (f16*)alloc((size_t)GG * HH * 2);
    f16*      outg16 = (f16*)alloc((size_t)GG * HH * 2);
    float*    adg    = (float*)alloc((size_t)GG * 4);
    int*      degb   = (int*)alloc((size_t)NN * 4);
    int*      rowptr = (int*)alloc((size_t)(NN + 1) * 4);
    unsigned* cursor = (unsigned*)alloc((size_t)NN * 4);
    int*      csr_src = (int*)alloc((size_t)EE * 4);
    int*      csr_eid = (int*)alloc((size_t)EE * 4);
    int*      bdeg   = (int*)alloc((size_t)GG * 4);
    int*      brow   = (int*)alloc((size_t)(GG + 1) * 4);
    int*      csum   = (int*)alloc(64 * 4);
    int*      choff  = (int*)alloc(65 * 4);
    float*    ve     = (float*)alloc(64);
    float*    eapart = (float*)alloc((size_t)EA_BLOCKS * 16 * 4);
    float*    vd     = (float*)alloc(HH * 4);
    float*    aloop  = (float*)alloc(64);
    f16*      lin1W16   = (f16*)alloc((size_t)HH * CIN * 2);
    f16*      conv0W16  = (f16*)alloc((size_t)HH * HH * 2);
    f16*      convsW16  = (f16*)alloc((size_t)2 * HH * HH * 2);
    f16*      gruWih16  = (f16*)alloc((size_t)3 * H3 * HH * 2);
    f16*      gruWhh16  = (f16*)alloc((size_t)3 * H3 * HH * 2);
    f16*      molWs16   = (f16*)alloc((size_t)HH * HH * 2);
    f16*      mgruWih16 = (f16*)alloc((size_t)H3 * HH * 2);
    f16*      mgruWhh16 = (f16*)alloc((size_t)H3 * HH * 2);
    // fragment-packed GRU weights (legacy layout; mol GRU uses slots 6,7)
    f16*      gruWihP   = (f16*)alloc((size_t)3 * FRAG_ELEMS * 8 * 2);
    f16*      gruWhhP   = (f16*)alloc((size_t)3 * FRAG_ELEMS * 8 * 2);
    f16*      mgruWihP  = (f16*)alloc((size_t)FRAG_ELEMS * 8 * 2);
    f16*      mgruWhhP  = (f16*)alloc((size_t)FRAG_ELEMS * 8 * 2);
    // gru4 combined (pass,chunk)-contiguous node-GRU weights: 3 layers x 442 KB
    f16*      gru4W     = (f16*)alloc((size_t)3 * G4_WLAYER * 2);
    if (off > ws_size) return;

    // ---- weight + input converts ----
    cvt_f2h<<<(NN * CIN + 255) / 256, 256, 0, stream>>>(x_in, xin16, NN * CIN);
    Cvt8 cv;
    cv.s[0] = lin1_W;   cv.d[0] = lin1W16;   cv.n[0] = HH * CIN;
    cv.s[1] = conv0_W;  cv.d[1] = conv0W16;  cv.n[1] = HH * HH;
    cv.s[2] = convs_W;  cv.d[2] = convsW16;  cv.n[2] = 2 * HH * HH;
    cv.s[3] = gru_Wih;  cv.d[3] = gruWih16;  cv.n[3] = 3 * H3 * HH;
    cv.s[4] = gru_Whh;  cv.d[4] = gruWhh16;  cv.n[4] = 3 * H3 * HH;
    cv.s[5] = mol_Wsrc; cv.d[5] = molWs16;   cv.n[5] = HH * HH;
    cv.s[6] = mgru_Wih; cv.d[6] = mgruWih16; cv.n[6] = H3 * HH;
    cv.s[7] = mgru_Whh; cv.d[7] = mgruWhh16; cv.n[7] = H3 * HH;
    cvt_multi<<<dim3((3 * H3 * HH + 255) / 256, 8), 256, 0, stream>>>(cv);

    // ---- pack mol GRU weights into legacy fragment-major layout ----
    Pack8 pk;
    const size_t WM = (size_t)H3 * HH;             // 110592 halves per matrix
    pk.s[0] = gruWih16;            pk.d[0] = gruWihP;
    pk.s[1] = gruWih16 + WM;       pk.d[1] = gruWihP + WM;
    pk.s[2] = gruWih16 + 2 * WM;   pk.d[2] = gruWihP + 2 * WM;
    pk.s[3] = gruWhh16;            pk.d[3] = gruWhhP;
    pk.s[4] = gruWhh16 + WM;       pk.d[4] = gruWhhP + WM;
    pk.s[5] = gruWhh16 + 2 * WM;   pk.d[5] = gruWhhP + 2 * WM;
    pk.s[6] = mgruWih16;           pk.d[6] = mgruWihP;
    pk.s[7] = mgruWhh16;           pk.d[7] = mgruWhhP;
    pack_frag<<<dim3((FRAG_ELEMS + 255) / 256, 8), 256, 0, stream>>>(pk);

    // ---- pack node GRU weights into gru4 (pass,chunk)-contiguous layout ----
    pack4<<<dim3(108, 3), 256, 0, stream>>>(gruWih16, gruWhh16, gru4W);

    // ---- CSR build ----
    const int nchunks = (NN + 1023) / 1024;   // 49
    hipMemsetAsync(degb, 0, NN * sizeof(int), stream);
    hist_kernel<<<(EE + 255) / 256, 256, 0, stream>>>(dst, degb, EE, NN);
    chunk_sum<<<nchunks, 256, 0, stream>>>(degb, csum, NN);
    scan_wave<<<1, 64, 0, stream>>>(csum, choff, nullptr, nchunks);
    local_scan<<<nchunks, 256, 0, stream>>>(degb, choff, rowptr, cursor, NN, nchunks);
    scatter_kernel<<<(EE + 255) / 256, 256, 0, stream>>>(src, dst, cursor, csr_src, csr_eid, EE);
    // batch scan (GG=2048): hierarchical (csum/choff reused sequentially on-stream)
    hipMemsetAsync(bdeg, 0, GG * sizeof(int), stream);
    hist_kernel<<<(NN + 255) / 256, 256, 0, stream>>>(batch, bdeg, NN, GG);
    chunk_sum<<<2, 256, 0, stream>>>(bdeg, csum, GG);
    scan_wave<<<1, 64, 0, stream>>>(csum, choff, nullptr, 2);
    local_scan<<<2, 256, 0, stream>>>(bdeg, choff, brow, nullptr, GG, 2);

    // ---- conv0 prep ----
    compose_vec2<<<(EDIM + 3) / 4, 256, 0, stream>>>(conv0_We, conv0_att_e, ve, HH, EDIM);
    ea_sum_kernel<<<EA_BLOCKS, 256, 0, stream>>>(eattr, eapart, EE);
    finalize_aloop<<<1, 256, 0, stream>>>(eapart, ve, aloop, 1.0f / EE, EA_BLOCKS);

    const dim3 gemmGrid((NN + 63) / 64, HH / 64);
    const int g4grid = (NN + G4_ROWS - 1) / G4_ROWS;   // 391

    // ping-pong node feature buffers (gru4 cannot write in place)
    f16* xcur = x16;
    f16* xnxt = x16b;

    // ---- lin1 ----
    gemm_mfma<<<gemmGrid, 256, 0, stream>>>(xin16, lin1W16, lin1_b, nullptr, xcur, NN, HH, CIN, 1);

    // ---- conv0 (edge feats + self loops, slope 0.2) ----
    gemm_mfma<<<gemmGrid, 256, 0, stream>>>(xcur, conv0W16, nullptr, nullptr, w16, NN, HH, HH, 0);
    row_dots_h<<<(NN + 3) / 4, 256, 0, stream>>>(w16, NN, conv0_att_s, asb, conv0_att_d, adb, nullptr);
    csr_aggregate<<<(NN + 3) / 4, 256, 0, stream>>>(rowptr, csr_src, csr_eid, NN, NN,
                                                    1, 0.2f, asb, adb, eattr, ve, aloop,
                                                    w16, conv0_b, h16);
    gru4_mfma<<<g4grid, 256, 0, stream>>>(h16, xcur, xnxt, gru4W, gru_bih, gru_bhh, NN);
    { f16* tmp = xcur; xcur = xnxt; xnxt = tmp; }

    // ---- remaining atom convs (no self loops, slope 0.01) ----
    for (int l = 0; l < 2; l++) {
        gemm_mfma<<<gemmGrid, 256, 0, stream>>>(xcur, convsW16 + (size_t)l * HH * HH,
                                                nullptr, nullptr, w16, NN, HH, HH, 0);
        row_dots_h<<<(NN + 3) / 4, 256, 0, stream>>>(w16, NN, convs_att_s + l * HH, asb,
                                                     convs_att_d + l * HH, adb, nullptr);
        csr_aggregate<<<(NN + 3) / 4, 256, 0, stream>>>(rowptr, csr_src, csr_eid, NN, NN,
                                                        0, 0.01f, asb, adb, nullptr, nullptr, nullptr,
                                                        w16, convs_b + l * HH, h16);
        gru4_mfma<<<g4grid, 256, 0, stream>>>(h16, xcur, xnxt,
                                              gru4W + (size_t)(l + 1) * G4_WLAYER,
                                              gru_bih + (size_t)(l + 1) * H3,
                                              gru_bhh + (size_t)(l + 1) * H3, NN);
        { f16* tmp = xcur; xcur = xnxt; xnxt = tmp; }
    }

    // ---- molecule readout ----
    pool_csr<<<(GG + 3) / 4, 256, 0, stream>>>(brow, xcur, outg16, GG);
    gemm_mfma<<<gemmGrid, 256, 0, stream>>>(xcur, molWs16, nullptr, nullptr, w16, NN, HH, HH, 0);
    row_dots_h<<<(NN + 3) / 4, 256, 0, stream>>>(w16, NN, mol_att_s, asb, nullptr, nullptr, nullptr);
    compose_vec2<<<(HH + 3) / 4, 256, 0, stream>>>(mol_Wdst, mol_att_d, vd, HH, HH);

    for (int t = 0; t < 2; t++) {
        row_dots_h<<<(GG + 3) / 4, 256, 0, stream>>>(outg16, GG, vd, adg, nullptr, nullptr, nullptr);
        csr_aggregate<<<(GG + 3) / 4, 256, 0, stream>>>(brow, nullptr, nullptr, GG, NN,
                                                        0, 0.01f, asb, adg, nullptr, nullptr, nullptr,
                                                        w16, mol_b, hg16);
        gru_mfma<<<(GG + 31) / 32, 256, 0, stream>>>(hg16, outg16, mgruWihP, mgruWhhP,
                                                     mgru_bih, mgru_bhh, GG);
    }

    // ---- final linear ----
    row_dots_h<<<(GG + 3) / 4, 256, 0, stream>>>(outg16, GG, lin2_W, (float*)d_out,
                                                 nullptr, nullptr, lin2_b);
}